// Round 1
// 489.796 us; speedup vs baseline: 1.0157x; 1.0157x over previous
//
#include <hip/hip_runtime.h>
#include <hip/hip_bf16.h>

// Problem constants: B=2, L=2048, D=2048, H=16, Dh=128, 3D=6144
typedef unsigned short ushort_t;
typedef __attribute__((ext_vector_type(4))) float fvec4;
typedef __attribute__((ext_vector_type(16))) float fvec16;
typedef __attribute__((ext_vector_type(8))) short short8;   // 8 bf16 (4 VGPRs) - MFMA A/B frag
typedef __attribute__((ext_vector_type(4))) unsigned short usvec4;
typedef __attribute__((ext_vector_type(2))) unsigned int uvec2;

typedef const __attribute__((address_space(1))) void* gas_ptr;
typedef __attribute__((address_space(3))) void* las_ptr;

__device__ __forceinline__ void glds16(const void* g, void* l) {
  // async global->LDS, 16B/lane, LDS dest = wave-uniform base + lane*16
  __builtin_amdgcn_global_load_lds((gas_ptr)g, (las_ptr)l, 16, 0, 0);
}

__device__ __forceinline__ ushort_t f2bf(float f) {
  unsigned u = __float_as_uint(f);
  u += 0x7FFFu + ((u >> 16) & 1u);   // RNE
  return (ushort_t)(u >> 16);
}
__device__ __forceinline__ float bf2f(ushort_t h) {
  return __uint_as_float(((unsigned)h) << 16);
}

// permlane32_swap: a' = [a.lo32lanes, b.lo32lanes], b' = [a.hi, b.hi]
__device__ __forceinline__ void swap32(unsigned& a, unsigned& b) {
#if __has_builtin(__builtin_amdgcn_permlane32_swap)
  uvec2 r = __builtin_amdgcn_permlane32_swap(a, b, false, false);
  a = r[0]; b = r[1];
#else
  const unsigned sa = (unsigned)__shfl_xor((int)a, 32);
  const unsigned sb = (unsigned)__shfl_xor((int)b, 32);
  const bool hi = (threadIdx.x & 32) != 0;
  const unsigned na = hi ? sb : a;
  const unsigned nb = hi ? b : sa;
  a = na; b = nb;
#endif
}

// ---------------------------------------------------------------- cast x -> bf16
__global__ __launch_bounds__(256) void cast_f32_bf16(const float* __restrict__ X,
                                                     ushort_t* __restrict__ Xb) {
  const size_t i = ((size_t)blockIdx.x * 256 + threadIdx.x) * 4;
  const fvec4 v = *(const fvec4*)(X + i);
  usvec4 o;
  o[0] = f2bf(v[0]); o[1] = f2bf(v[1]); o[2] = f2bf(v[2]); o[3] = f2bf(v[3]);
  *(usvec4*)(Xb + i) = o;
}

// ------------------------------------- transpose+cast weights: W(Kd,Nd) -> Wt(Nd,Kd) bf16
__global__ __launch_bounds__(256) void tcast(const float* __restrict__ W,
                                             ushort_t* __restrict__ Wt,
                                             const int Kd, const int Nd) {
  __shared__ float ls[64][65];
  const int t = threadIdx.x;
  const int n0 = blockIdx.x * 64, k0 = blockIdx.y * 64;
  const int kr = t >> 4, nc = (t & 15) * 4;
#pragma unroll
  for (int it = 0; it < 4; ++it) {
    const fvec4 v = *(const fvec4*)(W + (size_t)(k0 + it * 16 + kr) * Nd + n0 + nc);
    ls[it * 16 + kr][nc + 0] = v[0];
    ls[it * 16 + kr][nc + 1] = v[1];
    ls[it * 16 + kr][nc + 2] = v[2];
    ls[it * 16 + kr][nc + 3] = v[3];
  }
  __syncthreads();
  const int nr = t >> 2, kg = (t & 3) * 16;
  __align__(16) ushort_t tmp[16];
#pragma unroll
  for (int i = 0; i < 16; ++i) tmp[i] = f2bf(ls[kg + i][nr]);
  ushort_t* dst = Wt + (size_t)(n0 + nr) * Kd + k0 + kg;
  *(short8*)(dst)     = *(const short8*)(tmp);
  *(short8*)(dst + 8) = *(const short8*)(tmp + 8);
}

// ---------------------------------------------------------------- bf16 GEMM, B^T input
// C(M,N) = A(M,K) * Bt(N,K)^T.  128x128 tile, BK=64, 4 waves (2x2 of 64x64).
// 2-phase pipeline (T3-minimum): double-buffered LDS; next K-tile's
// global_load_lds is ISSUED before this K-tile's ds_read+MFMA, so the
// vmcnt(0) drain at the single per-iteration barrier is hidden under compute.
__global__ __launch_bounds__(256) void gemm_bt(
    const ushort_t* __restrict__ A, const ushort_t* __restrict__ Bt,
    const int M, const int N, const int K, const int mode,
    float* __restrict__ C,
    ushort_t* __restrict__ Qo, ushort_t* __restrict__ Ko, ushort_t* __restrict__ Vo) {
  __shared__ __align__(16) ushort_t lA[2][8192];
  __shared__ __align__(16) ushort_t lB[2][8192];
  const int tid = threadIdx.x, wv = tid >> 6, lane = tid & 63;
  const int quad = lane >> 4, mm = lane & 15;
  const int row0 = blockIdx.y * 128, col0 = blockIdx.x * 128;
  const int wr = wv >> 1, wc = wv & 1;

  const fvec4 FZ = {0.f, 0.f, 0.f, 0.f};
  fvec4 acc[4][4];
#pragma unroll
  for (int i = 0; i < 4; ++i)
#pragma unroll
    for (int j = 0; j < 4; ++j) acc[i][j] = FZ;

  // frag f = it*4+wv (wave-uniform): mt=f>>1 (16-row group), kc=f&1 (32-k half)
#define GEMM_STAGE(dA, dB, kk0)                                                       \
  _Pragma("unroll")                                                                   \
  for (int it = 0; it < 4; ++it) {                                                    \
    const int f_ = it * 4 + wv;                                                       \
    const int mt_ = f_ >> 1, kc_ = f_ & 1;                                            \
    glds16(A + (size_t)(row0 + mt_ * 16 + mm) * K + (kk0) + kc_ * 32 + quad * 8,      \
           (dA) + f_ * 512);                                                          \
    glds16(Bt + (size_t)(col0 + mt_ * 16 + mm) * K + (kk0) + kc_ * 32 + quad * 8,     \
           (dB) + f_ * 512);                                                          \
  }

  GEMM_STAGE(&lA[0][0], &lB[0][0], 0)
  __syncthreads();                       // drains vmcnt(0): tile 0 staged

  int cur = 0;
  for (int k0 = 0; k0 < K; k0 += 64) {
    if (k0 + 64 < K) {                   // issue next tile BEFORE compute
      GEMM_STAGE(&lA[cur ^ 1][0], &lB[cur ^ 1][0], k0 + 64)
    }
    const ushort_t* bA = &lA[cur][0];
    const ushort_t* bB = &lB[cur][0];
#pragma unroll
    for (int kc = 0; kc < 2; ++kc) {
      short8 af[4], bf[4];
#pragma unroll
      for (int i = 0; i < 4; ++i)
        af[i] = *(const short8*)(bA + ((wr * 4 + i) * 2 + kc) * 512 + lane * 8);
#pragma unroll
      for (int j = 0; j < 4; ++j)
        bf[j] = *(const short8*)(bB + ((wc * 4 + j) * 2 + kc) * 512 + lane * 8);
#pragma unroll
      for (int i = 0; i < 4; ++i)
#pragma unroll
        for (int j = 0; j < 4; ++j)
          acc[i][j] = __builtin_amdgcn_mfma_f32_16x16x32_bf16(af[i], bf[j], acc[i][j], 0, 0, 0);
    }
    __syncthreads();                     // loads had whole compute phase to land
    cur ^= 1;
  }
#undef GEMM_STAGE

  if (mode == 0) {
#pragma unroll
    for (int i = 0; i < 4; ++i)
#pragma unroll
      for (int r = 0; r < 4; ++r) {
        const int row = row0 + wr * 64 + i * 16 + quad * 4 + r;
        float* cr = C + (size_t)row * N + col0 + wc * 64;
#pragma unroll
        for (int j = 0; j < 4; ++j) cr[j * 16 + mm] = acc[i][j][r];
      }
  } else {
    const int which = col0 >> 11;            // 0:q 1:k 2:v
    const int h = (col0 >> 7) & 15;
    ushort_t* dst = (which == 0) ? Qo : (which == 1) ? Ko : Vo;
#pragma unroll
    for (int i = 0; i < 4; ++i)
#pragma unroll
      for (int r = 0; r < 4; ++r) {
        const int row = row0 + wr * 64 + i * 16 + quad * 4 + r;
        const int bb = row >> 11, l = row & 2047;
        ushort_t* dr = dst + ((size_t)(bb * 16 + h) * 2048 + l) * 128 + wc * 64;
#pragma unroll
        for (int j = 0; j < 4; ++j) dr[j * 16 + mm] = f2bf(acc[i][j][r]);
      }
  }
}

// ---------------------------------------------------------------- RoPE in-place on Q,K
// (B,H,L,Dh) bf16; pairs (d, d+64) share angle = l * 10000^(-d/64).
// blockIdx.y: 0 -> Q (also folds in softmax scale 1/sqrt(Dh)), 1 -> K.
__global__ __launch_bounds__(256) void rope_kernel(ushort_t* Qb, ushort_t* Kb) {
  const int gid = blockIdx.x * 256 + threadIdx.x;
  const int pd = gid & 63;
  const int row = gid >> 6;      // b*H*L + h*L + l
  const int l = row & 2047;
  ushort_t* base = (blockIdx.y ? Kb : Qb) + (size_t)row * 128;
  const float a = bf2f(base[pd]);
  const float bv = bf2f(base[pd + 64]);
  const float invf_rev = exp2f(-(float)pd * 0.20762050593045702f) * 0.15915494309189535f;
  float rev = (float)l * invf_rev;
  rev -= floorf(rev);                         // [0,1)
  const float ang = rev * 6.283185307179586f;
  float s, c;
  __sincosf(ang, &s, &c);
  float na = a * c - bv * s;
  float nb = bv * c + a * s;
  if (blockIdx.y == 0) { na *= 0.08838834764831845f; nb *= 0.08838834764831845f; }
  base[pd] = f2bf(na);
  base[pd + 64] = f2bf(nb);
}

// ---------------------------------------------------------------- V transpose per head
// Vn (B,H,L,Dh) -> Vt (B,H,Dh,L)
__global__ __launch_bounds__(256) void vtrans_kernel(const ushort_t* __restrict__ Vn,
                                                     ushort_t* __restrict__ Vt) {
  __shared__ ushort_t ls[128 * 132];
  const int bh = blockIdx.x >> 4;
  const int l0 = (blockIdx.x & 15) * 128;
  const int t = threadIdx.x;
  const ushort_t* src = Vn + ((size_t)bh * 2048 + l0) * 128;
#pragma unroll
  for (int it = 0; it < 16; ++it) {
    const int c = it * 256 + t;
    const int lr = c >> 5, dc = (c & 31) * 4;
    *(usvec4*)(ls + lr * 132 + dc) = *(const usvec4*)(src + lr * 128 + dc);
  }
  __syncthreads();
  ushort_t* dstb = Vt + (size_t)bh * 128 * 2048 + l0;
#pragma unroll
  for (int it = 0; it < 16; ++it) {
    const int c = it * 256 + t;
    const int d = c >> 5, lc = (c & 31) * 4;
    usvec4 o;
    o[0] = ls[(lc + 0) * 132 + d];
    o[1] = ls[(lc + 1) * 132 + d];
    o[2] = ls[(lc + 2) * 132 + d];
    o[3] = ls[(lc + 3) * 132 + d];
    *(usvec4*)(dstb + (size_t)d * 2048 + lc) = o;
  }
}

// ---------------------------------------------------------------- flash attention v2
// Block = (b,h, q-tile of 128). 4 waves; wave owns 32 q-rows. K/V tiles of 64 keys.
// 2-phase pipeline: K/V staging for tile t+1 issued into buf^1 before tile t's
// compute; single barrier per tile drains vmcnt under the MFMA+softmax work.
// S^T = K·Q^T via mfma_32x32x16 (C-layout: col=q=lane&31, row=key) so the PV
// A-operand needs only cvt_pk_bf16 + permlane32_swap — no LDS round-trip for P.
// Fixed-base softmax: no running max, no rescale.
__global__ __launch_bounds__(256, 2) void flash_kernel(
    const ushort_t* __restrict__ Qb, const ushort_t* __restrict__ Kb,
    const ushort_t* __restrict__ Vt, const int* __restrict__ am,
    ushort_t* __restrict__ Y) {
  __shared__ __align__(16) ushort_t lK[2][8192];   // 16 frags (ct*8+c): K A-operand layout
  __shared__ __align__(16) ushort_t lV[2][8192];   // 16 frags (dt*4+kc): V B-operand layout
  __shared__ float lds_l[128];

  const int tid = threadIdx.x, wv = tid >> 6, lane = tid & 63;
  const int lh = lane >> 5, cq = lane & 31;
  const int bid = blockIdx.x;
  const int bh = bid & 31;                 // spread bh across consecutive blocks (XCDs)
  const int qi = 15 - (bid >> 5);          // biggest q-tiles dispatch first
  const int b = bh >> 4, head = bh & 15;
  const size_t qkBase = (size_t)bh * (2048 * 128);
  const int qb = qi * 128 + wv * 32;       // wave's first q row
  const int q = qb + cq;                   // this lane's q (S^T col / PV m)

  // Q B-frags: lane holds Q[q][c*16 + lh*8 + j]
  short8 qf[8];
  {
    const ushort_t* qrow = Qb + qkBase + (size_t)q * 128;
#pragma unroll
    for (int c = 0; c < 8; ++c) qf[c] = *(const short8*)(qrow + c * 16 + lh * 8);
  }

  fvec16 yacc[4];
#pragma unroll
  for (int i = 0; i < 4; ++i)
#pragma unroll
    for (int r = 0; r < 16; ++r) yacc[i][r] = 0.f;
  float psum = 0.f;

#define FLASH_STAGE(dK, dV, kk0)                                                          \
  _Pragma("unroll")                                                                       \
  for (int it = 0; it < 4; ++it) {                                                        \
    const int f_ = it * 4 + wv;                                                           \
    const int ct_ = f_ >> 3, c_ = f_ & 7;                                                 \
    glds16(Kb + qkBase + (size_t)((kk0) + ct_ * 32 + cq) * 128 + c_ * 16 + lh * 8,        \
           (dK) + f_ * 512);                                                              \
    const int dt_ = f_ >> 2, kc_ = f_ & 3;                                                \
    glds16(Vt + ((size_t)bh * 128 + dt_ * 32 + cq) * 2048 + (kk0) + kc_ * 16 + lh * 8,    \
           (dV) + f_ * 512);                                                              \
  }

  const int nt = qi * 2 + 2;
  FLASH_STAGE(&lK[0][0], &lV[0][0], 0)
  __syncthreads();                         // tile 0 staged

  int cur = 0;
  for (int t = 0; t < nt; ++t) {
    const int k0 = t * 64;
    if (t + 1 < nt) {                      // issue next tile BEFORE compute
      FLASH_STAGE(&lK[cur ^ 1][0], &lV[cur ^ 1][0], k0 + 64)
    }

    if (k0 <= qb + 31) {                   // else tile fully causal-masked for this wave
      const ushort_t* bK = &lK[cur][0];
      const ushort_t* bV = &lV[cur][0];
      const int amv = am[b * 2048 + k0 + lane];
      const unsigned long long keymask = __ballot(amv != 0);
      const bool fullvalid = (k0 + 63 <= qb) && (keymask == ~0ull);

#pragma unroll
      for (int ct = 0; ct < 2; ++ct) {
        fvec16 sacc;
#pragma unroll
        for (int r = 0; r < 16; ++r) sacc[r] = 0.f;
        __builtin_amdgcn_s_setprio(1);
#pragma unroll
        for (int c = 0; c < 8; ++c) {
          short8 kf = *(const short8*)(bK + (ct * 8 + c) * 512 + lane * 8);
          sacc = __builtin_amdgcn_mfma_f32_32x32x16_bf16(kf, qf[c], sacc, 0, 0, 0);
        }
        __builtin_amdgcn_s_setprio(0);
        // S^T C-layout: value r is S[q][key] with key = (r&3)+8*(r>>2)+4*lh (+ct*32+k0)
        float p[16];
        if (fullvalid) {
#pragma unroll
          for (int r = 0; r < 16; ++r) p[r] = __expf(sacc[r]);
        } else {
#pragma unroll
          for (int r = 0; r < 16; ++r) {
            const int kl = (r & 3) + 8 * (r >> 2) + 4 * lh + ct * 32;
            const bool ok = (k0 + kl <= q) && (((keymask >> kl) & 1ull) != 0);
            p[r] = ok ? __expf(sacc[r]) : 0.f;
          }
        }
#pragma unroll
        for (int r = 0; r < 16; ++r) psum += p[r];
        // pack pairs of consecutive keys -> bf16x2
        unsigned pk[8];
#pragma unroll
        for (int j = 0; j < 8; ++j) {
          __hip_bfloat162 t2 = __float22bfloat162_rn(make_float2(p[2 * j], p[2 * j + 1]));
          pk[j] = *(unsigned*)&t2;           // low 16 bits = p[2j]
        }
        // permlane32_swap -> PV A-frags (keys cross the 32-lane halves; q stays put)
#pragma unroll
        for (int kc2 = 0; kc2 < 2; ++kc2) {
          unsigned a0 = pk[kc2 * 4 + 0], a2 = pk[kc2 * 4 + 2];
          unsigned a1 = pk[kc2 * 4 + 1], a3 = pk[kc2 * 4 + 3];
          swap32(a0, a2);
          swap32(a1, a3);
          union { unsigned u[4]; short8 s; } pf;
          pf.u[0] = a0; pf.u[1] = a1; pf.u[2] = a2; pf.u[3] = a3;
          const int kc = ct * 2 + kc2;
          __builtin_amdgcn_s_setprio(1);
#pragma unroll
          for (int dt = 0; dt < 4; ++dt) {
            short8 vf = *(const short8*)(bV + (dt * 4 + kc) * 512 + lane * 8);
            yacc[dt] = __builtin_amdgcn_mfma_f32_32x32x16_bf16(pf.s, vf, yacc[dt], 0, 0, 0);
          }
          __builtin_amdgcn_s_setprio(0);
        }
      }
    }
    __syncthreads();
    cur ^= 1;
  }
#undef FLASH_STAGE

  // denominator: combine the two key-halves, publish per-q, build 1/l per C-row
  psum += __shfl_xor(psum, 32);
  if (lane < 32) lds_l[wv * 32 + lane] = psum;
  float inv16[16];
#pragma unroll
  for (int r = 0; r < 16; ++r)
    inv16[r] = 1.f / lds_l[wv * 32 + (r & 3) + 8 * (r >> 2) + 4 * lh];

#pragma unroll
  for (int dt = 0; dt < 4; ++dt)
#pragma unroll
    for (int r = 0; r < 16; ++r) {
      const int qloc = (r & 3) + 8 * (r >> 2) + 4 * lh;
      ushort_t* dst = Y + ((size_t)(b * 2048 + qb + qloc)) * 2048 + head * 128 + dt * 32 + cq;
      *dst = f2bf(yacc[dt][r] * inv16[r]);
    }
}

// ---------------------------------------------------------------- launch
extern "C" void kernel_launch(void* const* d_in, const int* in_sizes, int n_in,
                              void* d_out, int out_size, void* d_ws, size_t ws_size,
                              hipStream_t stream) {
  const float* x      = (const float*)d_in[0];
  const int*   amask  = (const int*)d_in[1];
  const float* w_qkv  = (const float*)d_in[2];
  const float* w_proj = (const float*)d_in[3];

  // workspace layout (elements of bf16); Yb aliases xb, Vt aliases wqkvT
  ushort_t* xb     = (ushort_t*)d_ws;          // 8,388,608   (dead after gemm1)
  ushort_t* wqkvT  = xb + 8388608;             // 12,582,912  (dead after gemm1)
  ushort_t* wprojT = wqkvT + 12582912;         // 4,194,304
  ushort_t* Qb     = wprojT + 4194304;         // 8,388,608
  ushort_t* Kb     = Qb + 8388608;             // 8,388,608
  ushort_t* Vn     = Kb + 8388608;             // 8,388,608  -> total 96 MiB
  ushort_t* Vt     = wqkvT;                    // reuse
  ushort_t* Yb     = xb;                       // reuse

  cast_f32_bf16<<<8192, 256, 0, stream>>>(x, xb);
  tcast<<<dim3(96, 32), 256, 0, stream>>>(w_qkv, wqkvT, 2048, 6144);
  tcast<<<dim3(32, 32), 256, 0, stream>>>(w_proj, wprojT, 2048, 2048);
  gemm_bt<<<dim3(48, 32), 256, 0, stream>>>(xb, wqkvT, 4096, 6144, 2048, 1,
                                            nullptr, Qb, Kb, Vn);
  rope_kernel<<<dim3(16384, 2), 256, 0, stream>>>(Qb, Kb);
  vtrans_kernel<<<512, 256, 0, stream>>>(Vn, Vt);
  flash_kernel<<<512, 256, 0, stream>>>(Qb, Kb, Vt, amask, Yb);
  gemm_bt<<<dim3(16, 32), 256, 0, stream>>>(Yb, wprojT, 4096, 2048, 2048, 0,
                                            (float*)d_out, nullptr, nullptr, nullptr);
}

// Round 2
// 422.283 us; speedup vs baseline: 1.1781x; 1.1599x over previous
//
#include <hip/hip_runtime.h>
#include <hip/hip_bf16.h>

// Problem constants: B=2, L=2048, D=2048, H=16, Dh=128, 3D=6144
typedef unsigned short ushort_t;
typedef __attribute__((ext_vector_type(4))) float fvec4;
typedef __attribute__((ext_vector_type(16))) float fvec16;
typedef __attribute__((ext_vector_type(8))) short short8;   // 8 bf16 (4 VGPRs) - MFMA A/B frag
typedef __attribute__((ext_vector_type(4))) unsigned short usvec4;
typedef __attribute__((ext_vector_type(2))) unsigned int uvec2;

typedef const __attribute__((address_space(1))) void* gas_ptr;
typedef __attribute__((address_space(3))) void* las_ptr;

__device__ __forceinline__ void glds16(const void* g, void* l) {
  // async global->LDS, 16B/lane, LDS dest = wave-uniform base + lane*16
  __builtin_amdgcn_global_load_lds((gas_ptr)g, (las_ptr)l, 16, 0, 0);
}

__device__ __forceinline__ ushort_t f2bf(float f) {
  unsigned u = __float_as_uint(f);
  u += 0x7FFFu + ((u >> 16) & 1u);   // RNE
  return (ushort_t)(u >> 16);
}
__device__ __forceinline__ float bf2f(ushort_t h) {
  return __uint_as_float(((unsigned)h) << 16);
}

// permlane32_swap: a' = [a.lo32lanes, b.lo32lanes], b' = [a.hi, b.hi]
__device__ __forceinline__ void swap32(unsigned& a, unsigned& b) {
#if __has_builtin(__builtin_amdgcn_permlane32_swap)
  uvec2 r = __builtin_amdgcn_permlane32_swap(a, b, false, false);
  a = r[0]; b = r[1];
#else
  const unsigned sa = (unsigned)__shfl_xor((int)a, 32);
  const unsigned sb = (unsigned)__shfl_xor((int)b, 32);
  const bool hi = (threadIdx.x & 32) != 0;
  const unsigned na = hi ? sb : a;
  const unsigned nb = hi ? b : sa;
  a = na; b = nb;
#endif
}

// ---------------------------------------------------------------- cast x -> bf16
__global__ __launch_bounds__(256) void cast_f32_bf16(const float* __restrict__ X,
                                                     ushort_t* __restrict__ Xb) {
  const size_t i = ((size_t)blockIdx.x * 256 + threadIdx.x) * 4;
  const fvec4 v = *(const fvec4*)(X + i);
  usvec4 o;
  o[0] = f2bf(v[0]); o[1] = f2bf(v[1]); o[2] = f2bf(v[2]); o[3] = f2bf(v[3]);
  *(usvec4*)(Xb + i) = o;
}

// ------------------------------------- transpose+cast weights: W(Kd,Nd) -> Wt(Nd,Kd) bf16
__global__ __launch_bounds__(256) void tcast(const float* __restrict__ W,
                                             ushort_t* __restrict__ Wt,
                                             const int Kd, const int Nd) {
  __shared__ float ls[64][65];
  const int t = threadIdx.x;
  const int n0 = blockIdx.x * 64, k0 = blockIdx.y * 64;
  const int kr = t >> 4, nc = (t & 15) * 4;
#pragma unroll
  for (int it = 0; it < 4; ++it) {
    const fvec4 v = *(const fvec4*)(W + (size_t)(k0 + it * 16 + kr) * Nd + n0 + nc);
    ls[it * 16 + kr][nc + 0] = v[0];
    ls[it * 16 + kr][nc + 1] = v[1];
    ls[it * 16 + kr][nc + 2] = v[2];
    ls[it * 16 + kr][nc + 3] = v[3];
  }
  __syncthreads();
  const int nr = t >> 2, kg = (t & 3) * 16;
  __align__(16) ushort_t tmp[16];
#pragma unroll
  for (int i = 0; i < 16; ++i) tmp[i] = f2bf(ls[kg + i][nr]);
  ushort_t* dst = Wt + (size_t)(n0 + nr) * Kd + k0 + kg;
  *(short8*)(dst)     = *(const short8*)(tmp);
  *(short8*)(dst + 8) = *(const short8*)(tmp + 8);
}

// ================================================================ 256x256 8-phase GEMM
// C(M,N) = A(M,K) * Bt(N,K)^T.  BM=BN=256, BK=64, 512 threads = 8 waves (2Mx4N),
// per-wave output 128x64.  LDS 128 KiB: [slot2][mat2][256 lds-rows][64 ushorts].
//
// Row placement (per 256-row tile): global 64-row blocks {0,1,2,3} stored at lds
// blocks {0,2,1,3} so each 16KB "stage unit" (2x global_load_lds of 64 rows) covers
// the rows consumed by 2 consecutive compute quadrants of BOTH wave-rows:
//   unit u0 = global rows 0-63 & 128-191 (quadrants q0,q1), u1 = 64-127 & 192-255 (q2,q3).
//
// T2 swizzle (both-sides-or-neither, linear LDS dest for global_load_lds):
// data (row, kbyte) lives at phys (ldsrow, kbyte ^ ((row&7)<<4)); achieved by
// pre-swizzling the per-lane GLOBAL source k-chunk: src_chunk = (lane&7)^(lane>>3).
// Reads XOR the same pattern -> 8 lanes per 16B slot (optimal), no 16-way conflict.
//
// Schedule per iteration i (computes tiles 2i [slot0] and 2i+1 [slot1]):
//  ph1: rd B(2i)+A-q0 | stage Au1(2i+1)          ph5: rd B(2i+1)+A-q0 | stage Au1(2i+2)
//  ph2: rd A-q1       | stage Bh0(2i+2)          ph6: rd A-q1         | stage Bh0(2i+3)
//  ph3: rd A-q2       | stage Bh1(2i+2)          ph7: rd A-q2         | stage Bh1(2i+3)
//  ph4: rd A-q3       | stage Au0(2i+2) vmcnt(6) ph8: rd A-q3         | stage Au0(2i+3) vmcnt(6)
// Each phase: barrier; lgkmcnt(0); setprio(1); 16 MFMA; setprio(0); barrier.
// vmcnt(6) = 3 stage-units (2 loads each) in flight; every region staged lands
// >=3 phases before its first read; every overwrite targets a region whose
// readers passed a barrier in an earlier phase (checked unit-by-unit).
__device__ __forceinline__ void stage_unit(const ushort_t* __restrict__ G, const int rbase,
                                           const int K, const int tk,
                                           ushort_t* ldsmat, const int u,
                                           const int wv, const int lane) {
  const int rr = lane >> 3;                     // lane's row within 64-row chunk (mod 8 of row)
  const int kk = ((lane & 7) ^ rr) * 8;         // pre-swizzled global k-chunk (ushorts)
  const int r64 = wv * 8 + rr;
  glds16(G + (size_t)(rbase + u * 64 + r64) * K + tk + kk,
         ldsmat + (((u * 2 + 0) * 64 + wv * 8) * 64));
  glds16(G + (size_t)(rbase + 128 + u * 64 + r64) * K + tk + kk,
         ldsmat + (((u * 2 + 1) * 64 + wv * 8) * 64));
}

__device__ __forceinline__ short8 frag_ld(const ushort_t* ldsmat, const int rbase,
                                          const int kc, const int quad, const int mm) {
  const int r = rbase + mm;                     // global row within tile
  const int blk = r >> 6;
  const int pblk = ((blk & 1) << 1) | (blk >> 1);   // {0,1,2,3}->{0,2,1,3}
  const int ldsrow = pblk * 64 + (r & 63);
  const int kb = (kc * 64 + quad * 16) ^ ((mm & 7) << 4);   // swizzled byte-in-row
  return *(const short8*)(ldsmat + ldsrow * 64 + (kb >> 1));
}

#define FENCE asm volatile("" ::: "memory")

#define LDAF_DECL(q_, s_)                                                     \
  short8 af[2][2];                                                            \
  af[0][0] = frag_ld(&lds[s_][0][0], wr * 128 + (q_) * 32,      0, quad, mm); \
  af[0][1] = frag_ld(&lds[s_][0][0], wr * 128 + (q_) * 32,      1, quad, mm); \
  af[1][0] = frag_ld(&lds[s_][0][0], wr * 128 + (q_) * 32 + 16, 0, quad, mm); \
  af[1][1] = frag_ld(&lds[s_][0][0], wr * 128 + (q_) * 32 + 16, 1, quad, mm);

#define LDBF(s_)                                                              \
  _Pragma("unroll")                                                           \
  for (int j = 0; j < 4; ++j) {                                               \
    bfr[j][0] = frag_ld(&lds[s_][1][0], wc * 64 + j * 16, 0, quad, mm);       \
    bfr[j][1] = frag_ld(&lds[s_][1][0], wc * 64 + j * 16, 1, quad, mm);       \
  }

#define MFMA16(q_)                                                            \
  _Pragma("unroll")                                                           \
  for (int ii = 0; ii < 2; ++ii)                                              \
  _Pragma("unroll")                                                           \
  for (int j = 0; j < 4; ++j) {                                               \
    acc[(q_) * 2 + ii][j] = __builtin_amdgcn_mfma_f32_16x16x32_bf16(          \
        af[ii][0], bfr[j][0], acc[(q_) * 2 + ii][j], 0, 0, 0);                \
    acc[(q_) * 2 + ii][j] = __builtin_amdgcn_mfma_f32_16x16x32_bf16(          \
        af[ii][1], bfr[j][1], acc[(q_) * 2 + ii][j], 0, 0, 0);                \
  }

#define PH_SYNC_MFMA(q_)                                                      \
  __builtin_amdgcn_s_barrier();                                               \
  asm volatile("s_waitcnt lgkmcnt(0)" ::: "memory");                          \
  __builtin_amdgcn_s_setprio(1);                                              \
  MFMA16(q_);                                                                 \
  __builtin_amdgcn_s_setprio(0);                                              \
  __builtin_amdgcn_s_barrier();

__global__ __launch_bounds__(512, 2) void gemm256(
    const ushort_t* __restrict__ A, const ushort_t* __restrict__ Bt,
    const int M, const int N, const int K, const int mode,
    float* __restrict__ C,
    ushort_t* __restrict__ Qo, ushort_t* __restrict__ Ko, ushort_t* __restrict__ Vo) {
  __shared__ __align__(16) ushort_t lds[2][2][16384];   // [slot][A/B][256*64] = 128 KiB

  const int tid = threadIdx.x, wv = tid >> 6, lane = tid & 63;
  const int quad = lane >> 4, mm = lane & 15;
  const int wr = wv >> 2, wc = wv & 3;

  // XCD-aware block swizzle (grid size is a multiple of 8 for both call sites)
  const int nwg = gridDim.x, ntx = N >> 8;
  const int bid = blockIdx.x;
  const int swz = (bid & 7) * (nwg >> 3) + (bid >> 3);
  const int by = swz / ntx, bx = swz - by * ntx;
  const int row0 = by * 256, col0 = bx * 256;

  fvec4 acc[8][4];
#pragma unroll
  for (int i = 0; i < 8; ++i)
#pragma unroll
    for (int j = 0; j < 4; ++j) acc[i][j] = (fvec4){0.f, 0.f, 0.f, 0.f};

  short8 bfr[4][2];

  // ---- prologue: stage Bh0(0),Bh1(0),Au0(0),Au1(0),Bh0(1),Bh1(1),Au0(1)
  stage_unit(Bt, col0, K, 0,  &lds[0][1][0], 0, wv, lane); FENCE;
  stage_unit(Bt, col0, K, 0,  &lds[0][1][0], 1, wv, lane); FENCE;
  stage_unit(A,  row0, K, 0,  &lds[0][0][0], 0, wv, lane); FENCE;
  stage_unit(A,  row0, K, 0,  &lds[0][0][0], 1, wv, lane); FENCE;
  stage_unit(Bt, col0, K, 64, &lds[1][1][0], 0, wv, lane); FENCE;
  stage_unit(Bt, col0, K, 64, &lds[1][1][0], 1, wv, lane); FENCE;
  stage_unit(A,  row0, K, 64, &lds[1][0][0], 0, wv, lane); FENCE;
  asm volatile("s_waitcnt vmcnt(6)" ::: "memory");   // tile 0 fully landed
  __builtin_amdgcn_s_barrier();

  const int nit = K >> 7;                 // iterations of 2 K-tiles
  for (int i = 0; i < nit; ++i) {
    const bool more = (i + 1 < nit);
    const int kA = i * 128 + 64;          // tile 2i+1
    const int kB = i * 128 + 128;         // tile 2i+2
    const int kC = i * 128 + 192;         // tile 2i+3
    { // ph1
      LDAF_DECL(0, 0);
      LDBF(0);
      stage_unit(A, row0, K, kA, &lds[1][0][0], 1, wv, lane);
      PH_SYNC_MFMA(0);
    }
    { // ph2
      LDAF_DECL(1, 0);
      if (more) stage_unit(Bt, col0, K, kB, &lds[0][1][0], 0, wv, lane);
      PH_SYNC_MFMA(1);
    }
    { // ph3
      LDAF_DECL(2, 0);
      if (more) stage_unit(Bt, col0, K, kB, &lds[0][1][0], 1, wv, lane);
      PH_SYNC_MFMA(2);
    }
    { // ph4
      LDAF_DECL(3, 0);
      if (more) {
        stage_unit(A, row0, K, kB, &lds[0][0][0], 0, wv, lane);
        asm volatile("s_waitcnt vmcnt(6)" ::: "memory");
      } else {
        asm volatile("s_waitcnt vmcnt(0)" ::: "memory");
      }
      PH_SYNC_MFMA(3);
    }
    { // ph5
      LDAF_DECL(0, 1);
      LDBF(1);
      if (more) stage_unit(A, row0, K, kB, &lds[0][0][0], 1, wv, lane);
      PH_SYNC_MFMA(0);
    }
    { // ph6
      LDAF_DECL(1, 1);
      if (more) stage_unit(Bt, col0, K, kC, &lds[1][1][0], 0, wv, lane);
      PH_SYNC_MFMA(1);
    }
    { // ph7
      LDAF_DECL(2, 1);
      if (more) stage_unit(Bt, col0, K, kC, &lds[1][1][0], 1, wv, lane);
      PH_SYNC_MFMA(2);
    }
    { // ph8
      LDAF_DECL(3, 1);
      if (more) {
        stage_unit(A, row0, K, kC, &lds[1][0][0], 0, wv, lane);
        asm volatile("s_waitcnt vmcnt(6)" ::: "memory");
      }
      PH_SYNC_MFMA(3);
    }
  }

  // ---- epilogue
  if (mode == 0) {
#pragma unroll
    for (int i = 0; i < 8; ++i)
#pragma unroll
      for (int r = 0; r < 4; ++r) {
        const int row = row0 + wr * 128 + i * 16 + quad * 4 + r;
        float* cr = C + (size_t)row * N + col0 + wc * 64;
#pragma unroll
        for (int j = 0; j < 4; ++j) cr[j * 16 + mm] = acc[i][j][r];
      }
  } else {
    const int gcol = col0 + wc * 64;
    const int which = gcol >> 11;            // 0:q 1:k 2:v
    const int h = (gcol >> 7) & 15;
    const int coff = gcol & 127;
    ushort_t* dst = (which == 0) ? Qo : (which == 1) ? Ko : Vo;
#pragma unroll
    for (int i = 0; i < 8; ++i)
#pragma unroll
      for (int r = 0; r < 4; ++r) {
        const int row = row0 + wr * 128 + i * 16 + quad * 4 + r;
        const int bb = row >> 11, l = row & 2047;
        ushort_t* dr = dst + ((size_t)(bb * 16 + h) * 2048 + l) * 128 + coff;
#pragma unroll
        for (int j = 0; j < 4; ++j) dr[j * 16 + mm] = f2bf(acc[i][j][r]);
      }
  }
}

// ---------------------------------------------------------------- RoPE in-place on Q,K
// (B,H,L,Dh) bf16; pairs (d, d+64) share angle = l * 10000^(-d/64).
// blockIdx.y: 0 -> Q (also folds in softmax scale 1/sqrt(Dh)), 1 -> K.
__global__ __launch_bounds__(256) void rope_kernel(ushort_t* Qb, ushort_t* Kb) {
  const int gid = blockIdx.x * 256 + threadIdx.x;
  const int pd = gid & 63;
  const int row = gid >> 6;      // b*H*L + h*L + l
  const int l = row & 2047;
  ushort_t* base = (blockIdx.y ? Kb : Qb) + (size_t)row * 128;
  const float a = bf2f(base[pd]);
  const float bv = bf2f(base[pd + 64]);
  const float invf_rev = exp2f(-(float)pd * 0.20762050593045702f) * 0.15915494309189535f;
  float rev = (float)l * invf_rev;
  rev -= floorf(rev);                         // [0,1)
  const float ang = rev * 6.283185307179586f;
  float s, c;
  __sincosf(ang, &s, &c);
  float na = a * c - bv * s;
  float nb = bv * c + a * s;
  if (blockIdx.y == 0) { na *= 0.08838834764831845f; nb *= 0.08838834764831845f; }
  base[pd] = f2bf(na);
  base[pd + 64] = f2bf(nb);
}

// ---------------------------------------------------------------- V transpose per head
// Vn (B,H,L,Dh) -> Vt (B,H,Dh,L)
__global__ __launch_bounds__(256) void vtrans_kernel(const ushort_t* __restrict__ Vn,
                                                     ushort_t* __restrict__ Vt) {
  __shared__ ushort_t ls[128 * 132];
  const int bh = blockIdx.x >> 4;
  const int l0 = (blockIdx.x & 15) * 128;
  const int t = threadIdx.x;
  const ushort_t* src = Vn + ((size_t)bh * 2048 + l0) * 128;
#pragma unroll
  for (int it = 0; it < 16; ++it) {
    const int c = it * 256 + t;
    const int lr = c >> 5, dc = (c & 31) * 4;
    *(usvec4*)(ls + lr * 132 + dc) = *(const usvec4*)(src + lr * 128 + dc);
  }
  __syncthreads();
  ushort_t* dstb = Vt + (size_t)bh * 128 * 2048 + l0;
#pragma unroll
  for (int it = 0; it < 16; ++it) {
    const int c = it * 256 + t;
    const int d = c >> 5, lc = (c & 31) * 4;
    usvec4 o;
    o[0] = ls[(lc + 0) * 132 + d];
    o[1] = ls[(lc + 1) * 132 + d];
    o[2] = ls[(lc + 2) * 132 + d];
    o[3] = ls[(lc + 3) * 132 + d];
    *(usvec4*)(dstb + (size_t)d * 2048 + lc) = o;
  }
}

// ---------------------------------------------------------------- flash attention v2
// Block = (b,h, q-tile of 128). 4 waves; wave owns 32 q-rows. K/V tiles of 64 keys.
// 2-phase pipeline: K/V staging for tile t+1 issued into buf^1 before tile t's
// compute; single barrier per tile drains vmcnt under the MFMA+softmax work.
// S^T = K·Q^T via mfma_32x32x16 (C-layout: col=q=lane&31, row=key) so the PV
// A-operand needs only cvt_pk_bf16 + permlane32_swap — no LDS round-trip for P.
// Fixed-base softmax: no running max, no rescale.
__global__ __launch_bounds__(256, 2) void flash_kernel(
    const ushort_t* __restrict__ Qb, const ushort_t* __restrict__ Kb,
    const ushort_t* __restrict__ Vt, const int* __restrict__ am,
    ushort_t* __restrict__ Y) {
  __shared__ __align__(16) ushort_t lK[2][8192];   // 16 frags (ct*8+c): K A-operand layout
  __shared__ __align__(16) ushort_t lV[2][8192];   // 16 frags (dt*4+kc): V B-operand layout
  __shared__ float lds_l[128];

  const int tid = threadIdx.x, wv = tid >> 6, lane = tid & 63;
  const int lh = lane >> 5, cq = lane & 31;
  const int bid = blockIdx.x;
  const int bh = bid & 31;                 // spread bh across consecutive blocks (XCDs)
  const int qi = 15 - (bid >> 5);          // biggest q-tiles dispatch first
  const int b = bh >> 4, head = bh & 15;
  const size_t qkBase = (size_t)bh * (2048 * 128);
  const int qb = qi * 128 + wv * 32;       // wave's first q row
  const int q = qb + cq;                   // this lane's q (S^T col / PV m)

  // Q B-frags: lane holds Q[q][c*16 + lh*8 + j]
  short8 qf[8];
  {
    const ushort_t* qrow = Qb + qkBase + (size_t)q * 128;
#pragma unroll
    for (int c = 0; c < 8; ++c) qf[c] = *(const short8*)(qrow + c * 16 + lh * 8);
  }

  fvec16 yacc[4];
#pragma unroll
  for (int i = 0; i < 4; ++i)
#pragma unroll
    for (int r = 0; r < 16; ++r) yacc[i][r] = 0.f;
  float psum = 0.f;

#define FLASH_STAGE(dK, dV, kk0)                                                          \
  _Pragma("unroll")                                                                       \
  for (int it = 0; it < 4; ++it) {                                                        \
    const int f_ = it * 4 + wv;                                                           \
    const int ct_ = f_ >> 3, c_ = f_ & 7;                                                 \
    glds16(Kb + qkBase + (size_t)((kk0) + ct_ * 32 + cq) * 128 + c_ * 16 + lh * 8,        \
           (dK) + f_ * 512);                                                              \
    const int dt_ = f_ >> 2, kc_ = f_ & 3;                                                \
    glds16(Vt + ((size_t)bh * 128 + dt_ * 32 + cq) * 2048 + (kk0) + kc_ * 16 + lh * 8,    \
           (dV) + f_ * 512);                                                              \
  }

  const int nt = qi * 2 + 2;
  FLASH_STAGE(&lK[0][0], &lV[0][0], 0)
  __syncthreads();                         // tile 0 staged

  int cur = 0;
  for (int t = 0; t < nt; ++t) {
    const int k0 = t * 64;
    if (t + 1 < nt) {                      // issue next tile BEFORE compute
      FLASH_STAGE(&lK[cur ^ 1][0], &lV[cur ^ 1][0], k0 + 64)
    }

    if (k0 <= qb + 31) {                   // else tile fully causal-masked for this wave
      const ushort_t* bK = &lK[cur][0];
      const ushort_t* bV = &lV[cur][0];
      const int amv = am[b * 2048 + k0 + lane];
      const unsigned long long keymask = __ballot(amv != 0);
      const bool fullvalid = (k0 + 63 <= qb) && (keymask == ~0ull);

#pragma unroll
      for (int ct = 0; ct < 2; ++ct) {
        fvec16 sacc;
#pragma unroll
        for (int r = 0; r < 16; ++r) sacc[r] = 0.f;
        __builtin_amdgcn_s_setprio(1);
#pragma unroll
        for (int c = 0; c < 8; ++c) {
          short8 kf = *(const short8*)(bK + (ct * 8 + c) * 512 + lane * 8);
          sacc = __builtin_amdgcn_mfma_f32_32x32x16_bf16(kf, qf[c], sacc, 0, 0, 0);
        }
        __builtin_amdgcn_s_setprio(0);
        // S^T C-layout: value r is S[q][key] with key = (r&3)+8*(r>>2)+4*lh (+ct*32+k0)
        float p[16];
        if (fullvalid) {
#pragma unroll
          for (int r = 0; r < 16; ++r) p[r] = __expf(sacc[r]);
        } else {
#pragma unroll
          for (int r = 0; r < 16; ++r) {
            const int kl = (r & 3) + 8 * (r >> 2) + 4 * lh + ct * 32;
            const bool ok = (k0 + kl <= q) && (((keymask >> kl) & 1ull) != 0);
            p[r] = ok ? __expf(sacc[r]) : 0.f;
          }
        }
#pragma unroll
        for (int r = 0; r < 16; ++r) psum += p[r];
        // pack pairs of consecutive keys -> bf16x2
        unsigned pk[8];
#pragma unroll
        for (int j = 0; j < 8; ++j) {
          __hip_bfloat162 t2 = __float22bfloat162_rn(make_float2(p[2 * j], p[2 * j + 1]));
          pk[j] = *(unsigned*)&t2;           // low 16 bits = p[2j]
        }
        // permlane32_swap -> PV A-frags (keys cross the 32-lane halves; q stays put)
#pragma unroll
        for (int kc2 = 0; kc2 < 2; ++kc2) {
          unsigned a0 = pk[kc2 * 4 + 0], a2 = pk[kc2 * 4 + 2];
          unsigned a1 = pk[kc2 * 4 + 1], a3 = pk[kc2 * 4 + 3];
          swap32(a0, a2);
          swap32(a1, a3);
          union { unsigned u[4]; short8 s; } pf;
          pf.u[0] = a0; pf.u[1] = a1; pf.u[2] = a2; pf.u[3] = a3;
          const int kc = ct * 2 + kc2;
          __builtin_amdgcn_s_setprio(1);
#pragma unroll
          for (int dt = 0; dt < 4; ++dt) {
            short8 vf = *(const short8*)(bV + (dt * 4 + kc) * 512 + lane * 8);
            yacc[dt] = __builtin_amdgcn_mfma_f32_32x32x16_bf16(pf.s, vf, yacc[dt], 0, 0, 0);
          }
          __builtin_amdgcn_s_setprio(0);
        }
      }
    }
    __syncthreads();
    cur ^= 1;
  }
#undef FLASH_STAGE

  // denominator: combine the two key-halves, publish per-q, build 1/l per C-row
  psum += __shfl_xor(psum, 32);
  if (lane < 32) lds_l[wv * 32 + lane] = psum;
  float inv16[16];
#pragma unroll
  for (int r = 0; r < 16; ++r)
    inv16[r] = 1.f / lds_l[wv * 32 + (r & 3) + 8 * (r >> 2) + 4 * lh];

#pragma unroll
  for (int dt = 0; dt < 4; ++dt)
#pragma unroll
    for (int r = 0; r < 16; ++r) {
      const int qloc = (r & 3) + 8 * (r >> 2) + 4 * lh;
      ushort_t* dst = Y + ((size_t)(b * 2048 + qb + qloc)) * 2048 + head * 128 + dt * 32 + cq;
      *dst = f2bf(yacc[dt][r] * inv16[r]);
    }
}

// ---------------------------------------------------------------- launch
extern "C" void kernel_launch(void* const* d_in, const int* in_sizes, int n_in,
                              void* d_out, int out_size, void* d_ws, size_t ws_size,
                              hipStream_t stream) {
  const float* x      = (const float*)d_in[0];
  const int*   amask  = (const int*)d_in[1];
  const float* w_qkv  = (const float*)d_in[2];
  const float* w_proj = (const float*)d_in[3];

  // workspace layout (elements of bf16); Yb aliases xb, Vt aliases wqkvT
  ushort_t* xb     = (ushort_t*)d_ws;          // 8,388,608   (dead after gemm1)
  ushort_t* wqkvT  = xb + 8388608;             // 12,582,912  (dead after gemm1)
  ushort_t* wprojT = wqkvT + 12582912;         // 4,194,304
  ushort_t* Qb     = wprojT + 4194304;         // 8,388,608
  ushort_t* Kb     = Qb + 8388608;             // 8,388,608
  ushort_t* Vn     = Kb + 8388608;             // 8,388,608  -> total 96 MiB
  ushort_t* Vt     = wqkvT;                    // reuse
  ushort_t* Yb     = xb;                       // reuse

  cast_f32_bf16<<<8192, 256, 0, stream>>>(x, xb);
  tcast<<<dim3(96, 32), 256, 0, stream>>>(w_qkv, wqkvT, 2048, 6144);
  tcast<<<dim3(32, 32), 256, 0, stream>>>(w_proj, wprojT, 2048, 2048);
  gemm256<<<384, 512, 0, stream>>>(xb, wqkvT, 4096, 6144, 2048, 1,
                                   nullptr, Qb, Kb, Vn);
  rope_kernel<<<dim3(16384, 2), 256, 0, stream>>>(Qb, Kb);
  vtrans_kernel<<<512, 256, 0, stream>>>(Vn, Vt);
  flash_kernel<<<512, 256, 0, stream>>>(Qb, Kb, Vt, amask, Yb);
  gemm256<<<128, 512, 0, stream>>>(Yb, wprojT, 4096, 2048, 2048, 0,
                                   (float*)d_out, nullptr, nullptr, nullptr);
}

// Round 3
// 398.953 us; speedup vs baseline: 1.2469x; 1.0585x over previous
//
#include <hip/hip_runtime.h>
#include <hip/hip_bf16.h>

// Problem constants: B=2, L=2048, D=2048, H=16, Dh=128, 3D=6144
typedef unsigned short ushort_t;
typedef __attribute__((ext_vector_type(4))) float fvec4;
typedef __attribute__((ext_vector_type(16))) float fvec16;
typedef __attribute__((ext_vector_type(8))) short short8;   // 8 bf16 (4 VGPRs) - MFMA A/B frag
typedef __attribute__((ext_vector_type(4))) unsigned short usvec4;
typedef __attribute__((ext_vector_type(2))) unsigned int uvec2;

typedef const __attribute__((address_space(1))) void* gas_ptr;
typedef __attribute__((address_space(3))) void* las_ptr;

__device__ __forceinline__ void glds16(const void* g, void* l) {
  // async global->LDS, 16B/lane, LDS dest = wave-uniform base + lane*16
  __builtin_amdgcn_global_load_lds((gas_ptr)g, (las_ptr)l, 16, 0, 0);
}

__device__ __forceinline__ ushort_t f2bf(float f) {
  unsigned u = __float_as_uint(f);
  u += 0x7FFFu + ((u >> 16) & 1u);   // RNE
  return (ushort_t)(u >> 16);
}
__device__ __forceinline__ float bf2f(ushort_t h) {
  return __uint_as_float(((unsigned)h) << 16);
}

// permlane32_swap: a' = [a.lo32lanes, b.lo32lanes], b' = [a.hi, b.hi]
__device__ __forceinline__ void swap32(unsigned& a, unsigned& b) {
#if __has_builtin(__builtin_amdgcn_permlane32_swap)
  uvec2 r = __builtin_amdgcn_permlane32_swap(a, b, false, false);
  a = r[0]; b = r[1];
#else
  const unsigned sa = (unsigned)__shfl_xor((int)a, 32);
  const unsigned sb = (unsigned)__shfl_xor((int)b, 32);
  const bool hi = (threadIdx.x & 32) != 0;
  const unsigned na = hi ? sb : a;
  const unsigned nb = hi ? b : sa;
  a = na; b = nb;
#endif
}

// ---------------------------------------------------------------- cast x -> bf16
__global__ __launch_bounds__(256) void cast_f32_bf16(const float* __restrict__ X,
                                                     ushort_t* __restrict__ Xb) {
  const size_t i = ((size_t)blockIdx.x * 256 + threadIdx.x) * 4;
  const fvec4 v = *(const fvec4*)(X + i);
  usvec4 o;
  o[0] = f2bf(v[0]); o[1] = f2bf(v[1]); o[2] = f2bf(v[2]); o[3] = f2bf(v[3]);
  *(usvec4*)(Xb + i) = o;
}

// ------------------------------------- transpose+cast weights: W(Kd,Nd) -> Wt(Nd,Kd) bf16
__global__ __launch_bounds__(256) void tcast(const float* __restrict__ W,
                                             ushort_t* __restrict__ Wt,
                                             const int Kd, const int Nd) {
  __shared__ float ls[64][65];
  const int t = threadIdx.x;
  const int n0 = blockIdx.x * 64, k0 = blockIdx.y * 64;
  const int kr = t >> 4, nc = (t & 15) * 4;
#pragma unroll
  for (int it = 0; it < 4; ++it) {
    const fvec4 v = *(const fvec4*)(W + (size_t)(k0 + it * 16 + kr) * Nd + n0 + nc);
    ls[it * 16 + kr][nc + 0] = v[0];
    ls[it * 16 + kr][nc + 1] = v[1];
    ls[it * 16 + kr][nc + 2] = v[2];
    ls[it * 16 + kr][nc + 3] = v[3];
  }
  __syncthreads();
  const int nr = t >> 2, kg = (t & 3) * 16;
  __align__(16) ushort_t tmp[16];
#pragma unroll
  for (int i = 0; i < 16; ++i) tmp[i] = f2bf(ls[kg + i][nr]);
  ushort_t* dst = Wt + (size_t)(n0 + nr) * Kd + k0 + kg;
  *(short8*)(dst)     = *(const short8*)(tmp);
  *(short8*)(dst + 8) = *(const short8*)(tmp + 8);
}

// ================================================================ 256x256 8-phase GEMM
// C(M,N) = A(M,K) * Bt(N,K)^T.  BM=BN=256, BK=64, 512 threads = 8 waves (2Mx4N),
// per-wave output 128x64.  LDS 128 KiB: [slot2][mat2][256 lds-rows][64 ushorts].
//
// Row placement (per 256-row tile): global 64-row blocks {0,1,2,3} stored at lds
// blocks {0,2,1,3}: quadrants q0,q1 read lds rows 0-127 (unit u0), q2,q3 read
// lds rows 128-255 (unit u1) — so a unit's staging never overlaps the rows the
// current phase reads.
//
// T2 swizzle (both-sides-or-neither, linear LDS dest for global_load_lds):
// data (row, kbyte) lives at phys (ldsrow, kbyte ^ ((row&7)<<4)); achieved by
// pre-swizzling the per-lane GLOBAL source k-chunk: src_chunk = (lane&7)^(lane>>3).
// Reads XOR the same pattern -> 8 lanes per 16B slot, no 16-way conflict.
//
// ONE barrier per phase, NO explicit lgkmcnt(0) (round-3 change): per phase
// {barrier; ds_reads; stage glds; [vmcnt]; MFMA}. The compiler inserts counted
// lgkm waits per-use (DS completes in order), so MFMA overlaps the tail of this
// wave's reads and the sibling wave's LDS burst.  WAR ledger:
//  - every region read at phase p was vmcnt-guaranteed landed >=1 phase earlier
//    with a "memory"-clobber asm in between (ph4/ph8 vmcnt(6) covers slot
//    handoffs; within-slot regions landed a full iteration earlier);
//  - every stage at phase p writes rows disjoint from phase-p reads (checked
//    pair-by-pair; the {0,2,1,3} permute gives u0-stage || q3-read disjointness);
//  - cross-wave: wave Y passes barrier(p) only after its phase-(p-1) MFMA,
//    whose auto-wait completed Y's reads of any region staged at phase p.
//
// Schedule per iteration i (computes tiles 2i [slot0] and 2i+1 [slot1]):
//  ph1: rd B(2i)+A-q0 | stage Au1(2i+1)          ph5: rd B(2i+1)+A-q0 | stage Au1(2i+2)
//  ph2: rd A-q1       | stage Bh0(2i+2)          ph6: rd A-q1         | stage Bh0(2i+3)
//  ph3: rd A-q2       | stage Bh1(2i+2)          ph7: rd A-q2         | stage Bh1(2i+3)
//  ph4: rd A-q3       | stage Au0(2i+2) vmcnt(6) ph8: rd A-q3         | stage Au0(2i+3) vmcnt(6)
__device__ __forceinline__ void stage_unit(const ushort_t* __restrict__ G, const int rbase,
                                           const int K, const int tk,
                                           ushort_t* ldsmat, const int u,
                                           const int wv, const int lane) {
  const int rr = lane >> 3;                     // lane's row within 64-row chunk (mod 8 of row)
  const int kk = ((lane & 7) ^ rr) * 8;         // pre-swizzled global k-chunk (ushorts)
  const int r64 = wv * 8 + rr;
  glds16(G + (size_t)(rbase + u * 64 + r64) * K + tk + kk,
         ldsmat + (((u * 2 + 0) * 64 + wv * 8) * 64));
  glds16(G + (size_t)(rbase + 128 + u * 64 + r64) * K + tk + kk,
         ldsmat + (((u * 2 + 1) * 64 + wv * 8) * 64));
}

__device__ __forceinline__ short8 frag_ld(const ushort_t* ldsmat, const int rbase,
                                          const int kc, const int quad, const int mm) {
  const int r = rbase + mm;                     // global row within tile
  const int blk = r >> 6;
  const int pblk = ((blk & 1) << 1) | (blk >> 1);   // {0,1,2,3}->{0,2,1,3}
  const int ldsrow = pblk * 64 + (r & 63);
  const int kb = (kc * 64 + quad * 16) ^ ((mm & 7) << 4);   // swizzled byte-in-row
  return *(const short8*)(ldsmat + ldsrow * 64 + (kb >> 1));
}

#define FENCE asm volatile("" ::: "memory")

#define LD_A4(s_, q_)                                                         \
  short8 af[2][2];                                                            \
  af[0][0] = frag_ld(&lds[s_][0][0], wr * 128 + (q_) * 32,      0, quad, mm); \
  af[0][1] = frag_ld(&lds[s_][0][0], wr * 128 + (q_) * 32,      1, quad, mm); \
  af[1][0] = frag_ld(&lds[s_][0][0], wr * 128 + (q_) * 32 + 16, 0, quad, mm); \
  af[1][1] = frag_ld(&lds[s_][0][0], wr * 128 + (q_) * 32 + 16, 1, quad, mm);

#define LD_B8(s_)                                                             \
  _Pragma("unroll")                                                           \
  for (int j = 0; j < 4; ++j) {                                               \
    bfr[j][0] = frag_ld(&lds[s_][1][0], wc * 64 + j * 16, 0, quad, mm);       \
    bfr[j][1] = frag_ld(&lds[s_][1][0], wc * 64 + j * 16, 1, quad, mm);       \
  }

#define MFMA16(q_)                                                            \
  __builtin_amdgcn_s_setprio(1);                                              \
  _Pragma("unroll")                                                           \
  for (int ii = 0; ii < 2; ++ii)                                              \
  _Pragma("unroll")                                                           \
  for (int j = 0; j < 4; ++j) {                                               \
    acc[(q_) * 2 + ii][j] = __builtin_amdgcn_mfma_f32_16x16x32_bf16(          \
        af[ii][0], bfr[j][0], acc[(q_) * 2 + ii][j], 0, 0, 0);                \
    acc[(q_) * 2 + ii][j] = __builtin_amdgcn_mfma_f32_16x16x32_bf16(          \
        af[ii][1], bfr[j][1], acc[(q_) * 2 + ii][j], 0, 0, 0);                \
  }                                                                           \
  __builtin_amdgcn_s_setprio(0);

__global__ __launch_bounds__(512, 2) void gemm256(
    const ushort_t* __restrict__ A, const ushort_t* __restrict__ Bt,
    const int M, const int N, const int K, const int mode,
    float* __restrict__ C,
    ushort_t* __restrict__ Qo, ushort_t* __restrict__ Ko, ushort_t* __restrict__ Vo) {
  __shared__ __align__(16) ushort_t lds[2][2][16384];   // [slot][A/B][256*64] = 128 KiB

  const int tid = threadIdx.x, wv = tid >> 6, lane = tid & 63;
  const int quad = lane >> 4, mm = lane & 15;
  const int wr = wv >> 2, wc = wv & 3;

  // XCD-aware block swizzle (grid size is a multiple of 8 for both call sites)
  const int nwg = gridDim.x, ntx = N >> 8;
  const int bid = blockIdx.x;
  const int swz = (bid & 7) * (nwg >> 3) + (bid >> 3);
  const int by = swz / ntx, bx = swz - by * ntx;
  const int row0 = by * 256, col0 = bx * 256;

  fvec4 acc[8][4];
#pragma unroll
  for (int i = 0; i < 8; ++i)
#pragma unroll
    for (int j = 0; j < 4; ++j) acc[i][j] = (fvec4){0.f, 0.f, 0.f, 0.f};

  short8 bfr[4][2];

  // ---- prologue: stage Bh0(0),Bh1(0),Au0(0),Au1(0),Bh0(1),Bh1(1),Au0(1)
  stage_unit(Bt, col0, K, 0,  &lds[0][1][0], 0, wv, lane); FENCE;
  stage_unit(Bt, col0, K, 0,  &lds[0][1][0], 1, wv, lane); FENCE;
  stage_unit(A,  row0, K, 0,  &lds[0][0][0], 0, wv, lane); FENCE;
  stage_unit(A,  row0, K, 0,  &lds[0][0][0], 1, wv, lane); FENCE;
  stage_unit(Bt, col0, K, 64, &lds[1][1][0], 0, wv, lane); FENCE;
  stage_unit(Bt, col0, K, 64, &lds[1][1][0], 1, wv, lane); FENCE;
  stage_unit(A,  row0, K, 64, &lds[1][0][0], 0, wv, lane); FENCE;
  asm volatile("s_waitcnt vmcnt(6)" ::: "memory");   // tile 0 fully landed (per-wave)
  __builtin_amdgcn_s_barrier();                      // all waves' tile-0 stages landed

  const int nit = K >> 7;                 // iterations of 2 K-tiles
  for (int i = 0; i < nit; ++i) {
    const bool more = (i + 1 < nit);
    const int kA = i * 128 + 64;          // tile 2i+1
    const int kB = i * 128 + 128;         // tile 2i+2
    const int kC = i * 128 + 192;         // tile 2i+3
    { // ph1
      __builtin_amdgcn_s_barrier();
      LD_A4(0, 0);
      LD_B8(0);
      stage_unit(A, row0, K, kA, &lds[1][0][0], 1, wv, lane);
      MFMA16(0);
    }
    { // ph2
      __builtin_amdgcn_s_barrier();
      LD_A4(0, 1);
      if (more) stage_unit(Bt, col0, K, kB, &lds[0][1][0], 0, wv, lane);
      MFMA16(1);
    }
    { // ph3
      __builtin_amdgcn_s_barrier();
      LD_A4(0, 2);
      if (more) stage_unit(Bt, col0, K, kB, &lds[0][1][0], 1, wv, lane);
      MFMA16(2);
    }
    { // ph4
      __builtin_amdgcn_s_barrier();
      LD_A4(0, 3);
      if (more) {
        stage_unit(A, row0, K, kB, &lds[0][0][0], 0, wv, lane);
        asm volatile("s_waitcnt vmcnt(6)" ::: "memory");
      } else {
        asm volatile("s_waitcnt vmcnt(0)" ::: "memory");
      }
      MFMA16(3);
    }
    { // ph5
      __builtin_amdgcn_s_barrier();
      LD_A4(1, 0);
      LD_B8(1);
      if (more) stage_unit(A, row0, K, kB, &lds[0][0][0], 1, wv, lane);
      MFMA16(0);
    }
    { // ph6
      __builtin_amdgcn_s_barrier();
      LD_A4(1, 1);
      if (more) stage_unit(Bt, col0, K, kC, &lds[1][1][0], 0, wv, lane);
      MFMA16(1);
    }
    { // ph7
      __builtin_amdgcn_s_barrier();
      LD_A4(1, 2);
      if (more) stage_unit(Bt, col0, K, kC, &lds[1][1][0], 1, wv, lane);
      MFMA16(2);
    }
    { // ph8
      __builtin_amdgcn_s_barrier();
      LD_A4(1, 3);
      if (more) {
        stage_unit(A, row0, K, kC, &lds[1][0][0], 0, wv, lane);
        asm volatile("s_waitcnt vmcnt(6)" ::: "memory");
      }
      MFMA16(3);
    }
  }

  // ---- epilogue
  if (mode == 0) {
#pragma unroll
    for (int i = 0; i < 8; ++i)
#pragma unroll
      for (int r = 0; r < 4; ++r) {
        const int row = row0 + wr * 128 + i * 16 + quad * 4 + r;
        float* cr = C + (size_t)row * N + col0 + wc * 64;
#pragma unroll
        for (int j = 0; j < 4; ++j) cr[j * 16 + mm] = acc[i][j][r];
      }
  } else {
    const int gcol = col0 + wc * 64;
    const int which = gcol >> 11;            // 0:q 1:k 2:v
    const int h = (gcol >> 7) & 15;
    const int coff = gcol & 127;
    ushort_t* dst = (which == 0) ? Qo : (which == 1) ? Ko : Vo;
#pragma unroll
    for (int i = 0; i < 8; ++i)
#pragma unroll
      for (int r = 0; r < 4; ++r) {
        const int row = row0 + wr * 128 + i * 16 + quad * 4 + r;
        const int bb = row >> 11, l = row & 2047;
        ushort_t* dr = dst + ((size_t)(bb * 16 + h) * 2048 + l) * 128 + coff;
#pragma unroll
        for (int j = 0; j < 4; ++j) dr[j * 16 + mm] = f2bf(acc[i][j][r]);
      }
  }
}

// ---------------------------------------------------------------- RoPE in-place on Q,K
// (B,H,L,Dh) bf16; pairs (d, d+64) share angle = l * 10000^(-d/64).
// blockIdx.y: 0 -> Q (also folds in softmax scale 1/sqrt(Dh)), 1 -> K.
__global__ __launch_bounds__(256) void rope_kernel(ushort_t* Qb, ushort_t* Kb) {
  const int gid = blockIdx.x * 256 + threadIdx.x;
  const int pd = gid & 63;
  const int row = gid >> 6;      // b*H*L + h*L + l
  const int l = row & 2047;
  ushort_t* base = (blockIdx.y ? Kb : Qb) + (size_t)row * 128;
  const float a = bf2f(base[pd]);
  const float bv = bf2f(base[pd + 64]);
  const float invf_rev = exp2f(-(float)pd * 0.20762050593045702f) * 0.15915494309189535f;
  float rev = (float)l * invf_rev;
  rev -= floorf(rev);                         // [0,1)
  const float ang = rev * 6.283185307179586f;
  float s, c;
  __sincosf(ang, &s, &c);
  float na = a * c - bv * s;
  float nb = bv * c + a * s;
  if (blockIdx.y == 0) { na *= 0.08838834764831845f; nb *= 0.08838834764831845f; }
  base[pd] = f2bf(na);
  base[pd + 64] = f2bf(nb);
}

// ---------------------------------------------------------------- V transpose per head
// Vn (B,H,L,Dh) -> Vt (B,H,Dh,L)
__global__ __launch_bounds__(256) void vtrans_kernel(const ushort_t* __restrict__ Vn,
                                                     ushort_t* __restrict__ Vt) {
  __shared__ ushort_t ls[128 * 132];
  const int bh = blockIdx.x >> 4;
  const int l0 = (blockIdx.x & 15) * 128;
  const int t = threadIdx.x;
  const ushort_t* src = Vn + ((size_t)bh * 2048 + l0) * 128;
#pragma unroll
  for (int it = 0; it < 16; ++it) {
    const int c = it * 256 + t;
    const int lr = c >> 5, dc = (c & 31) * 4;
    *(usvec4*)(ls + lr * 132 + dc) = *(const usvec4*)(src + lr * 128 + dc);
  }
  __syncthreads();
  ushort_t* dstb = Vt + (size_t)bh * 128 * 2048 + l0;
#pragma unroll
  for (int it = 0; it < 16; ++it) {
    const int c = it * 256 + t;
    const int d = c >> 5, lc = (c & 31) * 4;
    usvec4 o;
    o[0] = ls[(lc + 0) * 132 + d];
    o[1] = ls[(lc + 1) * 132 + d];
    o[2] = ls[(lc + 2) * 132 + d];
    o[3] = ls[(lc + 3) * 132 + d];
    *(usvec4*)(dstb + (size_t)d * 2048 + lc) = o;
  }
}

// ---------------------------------------------------------------- flash attention v2
// Block = (b,h, q-tile of 128). 4 waves; wave owns 32 q-rows. K/V tiles of 64 keys.
// 2-phase pipeline: K/V staging for tile t+1 issued into buf^1 before tile t's
// compute; single barrier per tile drains vmcnt under the MFMA+softmax work.
// S^T = K·Q^T via mfma_32x32x16 (C-layout: col=q=lane&31, row=key) so the PV
// A-operand needs only cvt_pk_bf16 + permlane32_swap — no LDS round-trip for P.
// Fixed-base softmax: no running max, no rescale.
__global__ __launch_bounds__(256, 2) void flash_kernel(
    const ushort_t* __restrict__ Qb, const ushort_t* __restrict__ Kb,
    const ushort_t* __restrict__ Vt, const int* __restrict__ am,
    ushort_t* __restrict__ Y) {
  __shared__ __align__(16) ushort_t lK[2][8192];   // 16 frags (ct*8+c): K A-operand layout
  __shared__ __align__(16) ushort_t lV[2][8192];   // 16 frags (dt*4+kc): V B-operand layout
  __shared__ float lds_l[128];

  const int tid = threadIdx.x, wv = tid >> 6, lane = tid & 63;
  const int lh = lane >> 5, cq = lane & 31;
  const int bid = blockIdx.x;
  const int bh = bid & 31;                 // spread bh across consecutive blocks (XCDs)
  const int qi = 15 - (bid >> 5);          // biggest q-tiles dispatch first
  const int b = bh >> 4, head = bh & 15;
  const size_t qkBase = (size_t)bh * (2048 * 128);
  const int qb = qi * 128 + wv * 32;       // wave's first q row
  const int q = qb + cq;                   // this lane's q (S^T col / PV m)

  // Q B-frags: lane holds Q[q][c*16 + lh*8 + j]
  short8 qf[8];
  {
    const ushort_t* qrow = Qb + qkBase + (size_t)q * 128;
#pragma unroll
    for (int c = 0; c < 8; ++c) qf[c] = *(const short8*)(qrow + c * 16 + lh * 8);
  }

  fvec16 yacc[4];
#pragma unroll
  for (int i = 0; i < 4; ++i)
#pragma unroll
    for (int r = 0; r < 16; ++r) yacc[i][r] = 0.f;
  float psum = 0.f;

#define FLASH_STAGE(dK, dV, kk0)                                                          \
  _Pragma("unroll")                                                                       \
  for (int it = 0; it < 4; ++it) {                                                        \
    const int f_ = it * 4 + wv;                                                           \
    const int ct_ = f_ >> 3, c_ = f_ & 7;                                                 \
    glds16(Kb + qkBase + (size_t)((kk0) + ct_ * 32 + cq) * 128 + c_ * 16 + lh * 8,        \
           (dK) + f_ * 512);                                                              \
    const int dt_ = f_ >> 2, kc_ = f_ & 3;                                                \
    glds16(Vt + ((size_t)bh * 128 + dt_ * 32 + cq) * 2048 + (kk0) + kc_ * 16 + lh * 8,    \
           (dV) + f_ * 512);                                                              \
  }

  const int nt = qi * 2 + 2;
  FLASH_STAGE(&lK[0][0], &lV[0][0], 0)
  __syncthreads();                         // tile 0 staged

  int cur = 0;
  for (int t = 0; t < nt; ++t) {
    const int k0 = t * 64;
    if (t + 1 < nt) {                      // issue next tile BEFORE compute
      FLASH_STAGE(&lK[cur ^ 1][0], &lV[cur ^ 1][0], k0 + 64)
    }

    if (k0 <= qb + 31) {                   // else tile fully causal-masked for this wave
      const ushort_t* bK = &lK[cur][0];
      const ushort_t* bV = &lV[cur][0];
      const int amv = am[b * 2048 + k0 + lane];
      const unsigned long long keymask = __ballot(amv != 0);
      const bool fullvalid = (k0 + 63 <= qb) && (keymask == ~0ull);

#pragma unroll
      for (int ct = 0; ct < 2; ++ct) {
        fvec16 sacc;
#pragma unroll
        for (int r = 0; r < 16; ++r) sacc[r] = 0.f;
        __builtin_amdgcn_s_setprio(1);
#pragma unroll
        for (int c = 0; c < 8; ++c) {
          short8 kf = *(const short8*)(bK + (ct * 8 + c) * 512 + lane * 8);
          sacc = __builtin_amdgcn_mfma_f32_32x32x16_bf16(kf, qf[c], sacc, 0, 0, 0);
        }
        __builtin_amdgcn_s_setprio(0);
        // S^T C-layout: value r is S[q][key] with key = (r&3)+8*(r>>2)+4*lh (+ct*32+k0)
        float p[16];
        if (fullvalid) {
#pragma unroll
          for (int r = 0; r < 16; ++r) p[r] = __expf(sacc[r]);
        } else {
#pragma unroll
          for (int r = 0; r < 16; ++r) {
            const int kl = (r & 3) + 8 * (r >> 2) + 4 * lh + ct * 32;
            const bool ok = (k0 + kl <= q) && (((keymask >> kl) & 1ull) != 0);
            p[r] = ok ? __expf(sacc[r]) : 0.f;
          }
        }
#pragma unroll
        for (int r = 0; r < 16; ++r) psum += p[r];
        // pack pairs of consecutive keys -> bf16x2
        unsigned pk[8];
#pragma unroll
        for (int j = 0; j < 8; ++j) {
          __hip_bfloat162 t2 = __float22bfloat162_rn(make_float2(p[2 * j], p[2 * j + 1]));
          pk[j] = *(unsigned*)&t2;           // low 16 bits = p[2j]
        }
        // permlane32_swap -> PV A-frags (keys cross the 32-lane halves; q stays put)
#pragma unroll
        for (int kc2 = 0; kc2 < 2; ++kc2) {
          unsigned a0 = pk[kc2 * 4 + 0], a2 = pk[kc2 * 4 + 2];
          unsigned a1 = pk[kc2 * 4 + 1], a3 = pk[kc2 * 4 + 3];
          swap32(a0, a2);
          swap32(a1, a3);
          union { unsigned u[4]; short8 s; } pf;
          pf.u[0] = a0; pf.u[1] = a1; pf.u[2] = a2; pf.u[3] = a3;
          const int kc = ct * 2 + kc2;
          __builtin_amdgcn_s_setprio(1);
#pragma unroll
          for (int dt = 0; dt < 4; ++dt) {
            short8 vf = *(const short8*)(bV + (dt * 4 + kc) * 512 + lane * 8);
            yacc[dt] = __builtin_amdgcn_mfma_f32_32x32x16_bf16(pf.s, vf, yacc[dt], 0, 0, 0);
          }
          __builtin_amdgcn_s_setprio(0);
        }
      }
    }
    __syncthreads();
    cur ^= 1;
  }
#undef FLASH_STAGE

  // denominator: combine the two key-halves, publish per-q, build 1/l per C-row
  psum += __shfl_xor(psum, 32);
  if (lane < 32) lds_l[wv * 32 + lane] = psum;
  float inv16[16];
#pragma unroll
  for (int r = 0; r < 16; ++r)
    inv16[r] = 1.f / lds_l[wv * 32 + (r & 3) + 8 * (r >> 2) + 4 * lh];

#pragma unroll
  for (int dt = 0; dt < 4; ++dt)
#pragma unroll
    for (int r = 0; r < 16; ++r) {
      const int qloc = (r & 3) + 8 * (r >> 2) + 4 * lh;
      ushort_t* dst = Y + ((size_t)(b * 2048 + qb + qloc)) * 2048 + head * 128 + dt * 32 + cq;
      *dst = f2bf(yacc[dt][r] * inv16[r]);
    }
}

// ---------------------------------------------------------------- launch
extern "C" void kernel_launch(void* const* d_in, const int* in_sizes, int n_in,
                              void* d_out, int out_size, void* d_ws, size_t ws_size,
                              hipStream_t stream) {
  const float* x      = (const float*)d_in[0];
  const int*   amask  = (const int*)d_in[1];
  const float* w_qkv  = (const float*)d_in[2];
  const float* w_proj = (const float*)d_in[3];

  // workspace layout (elements of bf16); Yb aliases xb, Vt aliases wqkvT
  ushort_t* xb     = (ushort_t*)d_ws;          // 8,388,608   (dead after gemm1)
  ushort_t* wqkvT  = xb + 8388608;             // 12,582,912  (dead after gemm1)
  ushort_t* wprojT = wqkvT + 12582912;         // 4,194,304
  ushort_t* Qb     = wprojT + 4194304;         // 8,388,608
  ushort_t* Kb     = Qb + 8388608;             // 8,388,608
  ushort_t* Vn     = Kb + 8388608;             // 8,388,608  -> total 96 MiB
  ushort_t* Vt     = wqkvT;                    // reuse
  ushort_t* Yb     = xb;                       // reuse

  cast_f32_bf16<<<8192, 256, 0, stream>>>(x, xb);
  tcast<<<dim3(96, 32), 256, 0, stream>>>(w_qkv, wqkvT, 2048, 6144);
  tcast<<<dim3(32, 32), 256, 0, stream>>>(w_proj, wprojT, 2048, 2048);
  gemm256<<<384, 512, 0, stream>>>(xb, wqkvT, 4096, 6144, 2048, 1,
                                   nullptr, Qb, Kb, Vn);
  rope_kernel<<<dim3(16384, 2), 256, 0, stream>>>(Qb, Kb);
  vtrans_kernel<<<512, 256, 0, stream>>>(Vn, Vt);
  flash_kernel<<<512, 256, 0, stream>>>(Qb, Kb, Vt, amask, Yb);
  gemm256<<<128, 512, 0, stream>>>(Yb, wprojT, 4096, 2048, 2048, 0,
                                   (float*)d_out, nullptr, nullptr, nullptr);
}

// Round 4
// 390.716 us; speedup vs baseline: 1.2732x; 1.0211x over previous
//
#include <hip/hip_runtime.h>
#include <hip/hip_bf16.h>

// Problem constants: B=2, L=2048, D=2048, H=16, Dh=128, 3D=6144
typedef unsigned short ushort_t;
typedef __attribute__((ext_vector_type(4))) float fvec4;
typedef __attribute__((ext_vector_type(16))) float fvec16;
typedef __attribute__((ext_vector_type(8))) short short8;   // 8 bf16 (4 VGPRs) - MFMA A/B frag
typedef __attribute__((ext_vector_type(4))) unsigned short usvec4;
typedef __attribute__((ext_vector_type(2))) unsigned int uvec2;

typedef const __attribute__((address_space(1))) void* gas_ptr;
typedef __attribute__((address_space(3))) void* las_ptr;

__device__ __forceinline__ void glds16(const void* g, void* l) {
  // async global->LDS, 16B/lane, LDS dest = wave-uniform base + lane*16
  __builtin_amdgcn_global_load_lds((gas_ptr)g, (las_ptr)l, 16, 0, 0);
}

__device__ __forceinline__ ushort_t f2bf(float f) {
  unsigned u = __float_as_uint(f);
  u += 0x7FFFu + ((u >> 16) & 1u);   // RNE
  return (ushort_t)(u >> 16);
}
__device__ __forceinline__ float bf2f(ushort_t h) {
  return __uint_as_float(((unsigned)h) << 16);
}

// permlane32_swap: a' = [a.lo32lanes, b.lo32lanes], b' = [a.hi, b.hi]
__device__ __forceinline__ void swap32(unsigned& a, unsigned& b) {
#if __has_builtin(__builtin_amdgcn_permlane32_swap)
  uvec2 r = __builtin_amdgcn_permlane32_swap(a, b, false, false);
  a = r[0]; b = r[1];
#else
  const unsigned sa = (unsigned)__shfl_xor((int)a, 32);
  const unsigned sb = (unsigned)__shfl_xor((int)b, 32);
  const bool hi = (threadIdx.x & 32) != 0;
  const unsigned na = hi ? sb : a;
  const unsigned nb = hi ? b : sa;
  a = na; b = nb;
#endif
}

// ---------------------------------------------------------------- cast x -> bf16
__global__ __launch_bounds__(256) void cast_f32_bf16(const float* __restrict__ X,
                                                     ushort_t* __restrict__ Xb) {
  const size_t i = ((size_t)blockIdx.x * 256 + threadIdx.x) * 4;
  const fvec4 v = *(const fvec4*)(X + i);
  usvec4 o;
  o[0] = f2bf(v[0]); o[1] = f2bf(v[1]); o[2] = f2bf(v[2]); o[3] = f2bf(v[3]);
  *(usvec4*)(Xb + i) = o;
}

// ------------------------------------- transpose+cast weights: W(Kd,Nd) -> Wt(Nd,Kd) bf16
__global__ __launch_bounds__(256) void tcast(const float* __restrict__ W,
                                             ushort_t* __restrict__ Wt,
                                             const int Kd, const int Nd) {
  __shared__ float ls[64][65];
  const int t = threadIdx.x;
  const int n0 = blockIdx.x * 64, k0 = blockIdx.y * 64;
  const int kr = t >> 4, nc = (t & 15) * 4;
#pragma unroll
  for (int it = 0; it < 4; ++it) {
    const fvec4 v = *(const fvec4*)(W + (size_t)(k0 + it * 16 + kr) * Nd + n0 + nc);
    ls[it * 16 + kr][nc + 0] = v[0];
    ls[it * 16 + kr][nc + 1] = v[1];
    ls[it * 16 + kr][nc + 2] = v[2];
    ls[it * 16 + kr][nc + 3] = v[3];
  }
  __syncthreads();
  const int nr = t >> 2, kg = (t & 3) * 16;
  __align__(16) ushort_t tmp[16];
#pragma unroll
  for (int i = 0; i < 16; ++i) tmp[i] = f2bf(ls[kg + i][nr]);
  ushort_t* dst = Wt + (size_t)(n0 + nr) * Kd + k0 + kg;
  *(short8*)(dst)     = *(const short8*)(tmp);
  *(short8*)(dst + 8) = *(const short8*)(tmp + 8);
}

#define FENCE asm volatile("" ::: "memory")

// ================================================================ 256x256 8-phase GEMM
// (kept as revert path; unused this round — see gemm128 below)
__device__ __forceinline__ void stage_unit(const ushort_t* __restrict__ G, const int rbase,
                                           const int K, const int tk,
                                           ushort_t* ldsmat, const int u,
                                           const int wv, const int lane) {
  const int rr = lane >> 3;
  const int kk = ((lane & 7) ^ rr) * 8;
  const int r64 = wv * 8 + rr;
  glds16(G + (size_t)(rbase + u * 64 + r64) * K + tk + kk,
         ldsmat + (((u * 2 + 0) * 64 + wv * 8) * 64));
  glds16(G + (size_t)(rbase + 128 + u * 64 + r64) * K + tk + kk,
         ldsmat + (((u * 2 + 1) * 64 + wv * 8) * 64));
}

__device__ __forceinline__ short8 frag_ld(const ushort_t* ldsmat, const int rbase,
                                          const int kc, const int quad, const int mm) {
  const int r = rbase + mm;
  const int blk = r >> 6;
  const int pblk = ((blk & 1) << 1) | (blk >> 1);
  const int ldsrow = pblk * 64 + (r & 63);
  const int kb = (kc * 64 + quad * 16) ^ ((mm & 7) << 4);
  return *(const short8*)(ldsmat + ldsrow * 64 + (kb >> 1));
}

#define LD_A4(s_, q_)                                                         \
  short8 af[2][2];                                                            \
  af[0][0] = frag_ld(&lds[s_][0][0], wr * 128 + (q_) * 32,      0, quad, mm); \
  af[0][1] = frag_ld(&lds[s_][0][0], wr * 128 + (q_) * 32,      1, quad, mm); \
  af[1][0] = frag_ld(&lds[s_][0][0], wr * 128 + (q_) * 32 + 16, 0, quad, mm); \
  af[1][1] = frag_ld(&lds[s_][0][0], wr * 128 + (q_) * 32 + 16, 1, quad, mm);

#define LD_B8(s_)                                                             \
  _Pragma("unroll")                                                           \
  for (int j = 0; j < 4; ++j) {                                               \
    bfr[j][0] = frag_ld(&lds[s_][1][0], wc * 64 + j * 16, 0, quad, mm);       \
    bfr[j][1] = frag_ld(&lds[s_][1][0], wc * 64 + j * 16, 1, quad, mm);       \
  }

#define MFMA16(q_)                                                            \
  __builtin_amdgcn_s_setprio(1);                                              \
  _Pragma("unroll")                                                           \
  for (int ii = 0; ii < 2; ++ii)                                              \
  _Pragma("unroll")                                                           \
  for (int j = 0; j < 4; ++j) {                                               \
    acc[(q_) * 2 + ii][j] = __builtin_amdgcn_mfma_f32_16x16x32_bf16(          \
        af[ii][0], bfr[j][0], acc[(q_) * 2 + ii][j], 0, 0, 0);                \
    acc[(q_) * 2 + ii][j] = __builtin_amdgcn_mfma_f32_16x16x32_bf16(          \
        af[ii][1], bfr[j][1], acc[(q_) * 2 + ii][j], 0, 0, 0);                \
  }                                                                           \
  __builtin_amdgcn_s_setprio(0);

__global__ __launch_bounds__(512, 2) void gemm256(
    const ushort_t* __restrict__ A, const ushort_t* __restrict__ Bt,
    const int M, const int N, const int K, const int mode,
    float* __restrict__ C,
    ushort_t* __restrict__ Qo, ushort_t* __restrict__ Ko, ushort_t* __restrict__ Vo) {
  __shared__ __align__(16) ushort_t lds[2][2][16384];

  const int tid = threadIdx.x, wv = tid >> 6, lane = tid & 63;
  const int quad = lane >> 4, mm = lane & 15;
  const int wr = wv >> 2, wc = wv & 3;

  const int nwg = gridDim.x, ntx = N >> 8;
  const int bid = blockIdx.x;
  const int swz = (bid & 7) * (nwg >> 3) + (bid >> 3);
  const int by = swz / ntx, bx = swz - by * ntx;
  const int row0 = by * 256, col0 = bx * 256;

  fvec4 acc[8][4];
#pragma unroll
  for (int i = 0; i < 8; ++i)
#pragma unroll
    for (int j = 0; j < 4; ++j) acc[i][j] = (fvec4){0.f, 0.f, 0.f, 0.f};

  short8 bfr[4][2];

  stage_unit(Bt, col0, K, 0,  &lds[0][1][0], 0, wv, lane); FENCE;
  stage_unit(Bt, col0, K, 0,  &lds[0][1][0], 1, wv, lane); FENCE;
  stage_unit(A,  row0, K, 0,  &lds[0][0][0], 0, wv, lane); FENCE;
  stage_unit(A,  row0, K, 0,  &lds[0][0][0], 1, wv, lane); FENCE;
  stage_unit(Bt, col0, K, 64, &lds[1][1][0], 0, wv, lane); FENCE;
  stage_unit(Bt, col0, K, 64, &lds[1][1][0], 1, wv, lane); FENCE;
  stage_unit(A,  row0, K, 64, &lds[1][0][0], 0, wv, lane); FENCE;
  asm volatile("s_waitcnt vmcnt(6)" ::: "memory");
  __builtin_amdgcn_s_barrier();

  const int nit = K >> 7;
  for (int i = 0; i < nit; ++i) {
    const bool more = (i + 1 < nit);
    const int kA = i * 128 + 64;
    const int kB = i * 128 + 128;
    const int kC = i * 128 + 192;
    { __builtin_amdgcn_s_barrier();
      LD_A4(0, 0); LD_B8(0);
      stage_unit(A, row0, K, kA, &lds[1][0][0], 1, wv, lane);
      MFMA16(0); }
    { __builtin_amdgcn_s_barrier();
      LD_A4(0, 1);
      if (more) stage_unit(Bt, col0, K, kB, &lds[0][1][0], 0, wv, lane);
      MFMA16(1); }
    { __builtin_amdgcn_s_barrier();
      LD_A4(0, 2);
      if (more) stage_unit(Bt, col0, K, kB, &lds[0][1][0], 1, wv, lane);
      MFMA16(2); }
    { __builtin_amdgcn_s_barrier();
      LD_A4(0, 3);
      if (more) { stage_unit(A, row0, K, kB, &lds[0][0][0], 0, wv, lane);
        asm volatile("s_waitcnt vmcnt(6)" ::: "memory");
      } else { asm volatile("s_waitcnt vmcnt(0)" ::: "memory"); }
      MFMA16(3); }
    { __builtin_amdgcn_s_barrier();
      LD_A4(1, 0); LD_B8(1);
      if (more) stage_unit(A, row0, K, kB, &lds[0][0][0], 1, wv, lane);
      MFMA16(0); }
    { __builtin_amdgcn_s_barrier();
      LD_A4(1, 1);
      if (more) stage_unit(Bt, col0, K, kC, &lds[1][1][0], 0, wv, lane);
      MFMA16(1); }
    { __builtin_amdgcn_s_barrier();
      LD_A4(1, 2);
      if (more) stage_unit(Bt, col0, K, kC, &lds[1][1][0], 1, wv, lane);
      MFMA16(2); }
    { __builtin_amdgcn_s_barrier();
      LD_A4(1, 3);
      if (more) { stage_unit(A, row0, K, kC, &lds[1][0][0], 0, wv, lane);
        asm volatile("s_waitcnt vmcnt(6)" ::: "memory"); }
      MFMA16(3); }
  }

  if (mode == 0) {
#pragma unroll
    for (int i = 0; i < 8; ++i)
#pragma unroll
      for (int r = 0; r < 4; ++r) {
        const int row = row0 + wr * 128 + i * 16 + quad * 4 + r;
        float* cr = C + (size_t)row * N + col0 + wc * 64;
#pragma unroll
        for (int j = 0; j < 4; ++j) cr[j * 16 + mm] = acc[i][j][r];
      }
  } else {
    const int gcol = col0 + wc * 64;
    const int which = gcol >> 11;
    const int h = (gcol >> 7) & 15;
    const int coff = gcol & 127;
    ushort_t* dst = (which == 0) ? Qo : (which == 1) ? Ko : Vo;
#pragma unroll
    for (int i = 0; i < 8; ++i)
#pragma unroll
      for (int r = 0; r < 4; ++r) {
        const int row = row0 + wr * 128 + i * 16 + quad * 4 + r;
        const int bb = row >> 11, l = row & 2047;
        ushort_t* dr = dst + ((size_t)(bb * 16 + h) * 2048 + l) * 128 + coff;
#pragma unroll
        for (int j = 0; j < 4; ++j) dr[j * 16 + mm] = f2bf(acc[i][j][r]);
      }
  }
}

// ================================================================ 128x256 4-phase GEMM
// BM=128, BN=256, BK=64, 512 thr = 8 waves (2M x 4N), per-wave 64x64 output.
// LDS 96 KiB: [slot2][ A 128x64 | B 256x64 ] ushorts, IDENTITY row layout
// (B fully register-resident per tile after its read phase, so no block permute
// needed; A staged in one call, B in two).  Swizzle identical to gemm256
// (pre-swizzled global k-chunk (lane&7)^(lane>>3); read XOR (row&7)<<4).
//
// Grid quantization motivation: QKV = 32x24 = 768 blocks = 3 EXACT rounds;
// proj = 32x8 = 256 blocks = 1 full round (vs 128 half-idle at 256x256).
//
// Phase schedule per iteration i (tiles 2i in slot0, 2i+1 in slot1), one raw
// barrier per phase, reads AFTER barrier, MFMA last:
//  ph1: stage A(2i+1->s1)           | rd s0: A-kc0 (4) + B both kc (8) | MFMA kc0 | lgkm0
//  ph2: stage B(2i+2->s0) vmcnt(4)  | rd s0: A-kc1 (4)                 | MFMA kc1
//  ph3: stage A(2i+2->s0)           | rd s1: A-kc0 + B (12)            | MFMA kc0 | lgkm0
//  ph4: stage B(2i+3->s1) vmcnt(4)  | rd s1: A-kc1 (4)                 | MFMA kc1
// vmcnt ledger (2 loads per A-call, 4 per B-pair; issue order fixed):
//  ph2's vmcnt(4) leaves only ph2's B outstanding -> confirms A(2i+1)@ph1 and
//  B(2i+1)@ph4' one barrier before ph3 reads s1.  ph4's vmcnt(4) confirms
//  B(2i+2)@ph2 + A(2i+2)@ph3 one barrier before next-ph1 reads s0.
// WAR: ph1's lgkm0 drains in-flight B-kc1 ds_reads before ph2 overwrites s0-B
//  (cross-wave safe: barrier separates); same for ph3/ph4 on s1-B.  A regions
//  are fully consumed by the MFMA of their read phase (auto lgkm drain).
__device__ __forceinline__ void stage_a128(const ushort_t* __restrict__ G, const int row0,
                                           const int K, const int tk, ushort_t* ldsA,
                                           const int wv, const int lane) {
  const int rr = lane >> 3;
  const int kk = ((lane & 7) ^ rr) * 8;
  const int r = wv * 8 + rr;
  glds16(G + (size_t)(row0 + r) * K + tk + kk,      ldsA + (wv * 8) * 64);
  glds16(G + (size_t)(row0 + 64 + r) * K + tk + kk, ldsA + (64 + wv * 8) * 64);
}
__device__ __forceinline__ void stage_b128(const ushort_t* __restrict__ G, const int col0,
                                           const int K, const int tk, ushort_t* ldsB,
                                           const int u, const int wv, const int lane) {
  const int rr = lane >> 3;
  const int kk = ((lane & 7) ^ rr) * 8;
  const int r = u * 64 + wv * 8 + rr;
  glds16(G + (size_t)(col0 + r) * K + tk + kk,       ldsB + (u * 64 + wv * 8) * 64);
  glds16(G + (size_t)(col0 + 128 + r) * K + tk + kk, ldsB + (128 + u * 64 + wv * 8) * 64);
}
__device__ __forceinline__ short8 fragld128(const ushort_t* mat, const int row,
                                            const int kc, const int quad) {
  const int kb = (kc * 64 + quad * 16) ^ ((row & 7) << 4);
  return *(const short8*)(mat + row * 64 + (kb >> 1));
}

__global__ __launch_bounds__(512, 2) void gemm128(
    const ushort_t* __restrict__ A, const ushort_t* __restrict__ Bt,
    const int M, const int N, const int K, const int mode,
    float* __restrict__ C,
    ushort_t* __restrict__ Qo, ushort_t* __restrict__ Ko, ushort_t* __restrict__ Vo) {
  __shared__ __align__(16) ushort_t l128[2][24576];   // per slot: A[0..8191], B[8192..24575]

  const int tid = threadIdx.x, wv = tid >> 6, lane = tid & 63;
  const int quad = lane >> 4, mm = lane & 15;
  const int wr = wv >> 2, wc = wv & 3;   // 2M x 4N

  const int nwg = gridDim.x, ntx = N >> 8;
  const int bid = blockIdx.x;
  const int swz = (bid & 7) * (nwg >> 3) + (bid >> 3);
  const int by = swz / ntx, bx = swz - by * ntx;
  const int row0 = by * 128, col0 = bx * 256;

  fvec4 acc[4][4];
#pragma unroll
  for (int m = 0; m < 4; ++m)
#pragma unroll
    for (int j = 0; j < 4; ++j) acc[m][j] = (fvec4){0.f, 0.f, 0.f, 0.f};

  ushort_t* A0 = &l128[0][0];     ushort_t* B0 = &l128[0][8192];
  ushort_t* A1 = &l128[1][0];     ushort_t* B1 = &l128[1][8192];

  short8 bfr[4][2];

  // prologue: B(t0), A(t0), B(t1) = 10 loads; keep newest 4 (B(t1)) in flight
  stage_b128(Bt, col0, K, 0,  B0, 0, wv, lane); FENCE;
  stage_b128(Bt, col0, K, 0,  B0, 1, wv, lane); FENCE;
  stage_a128(A,  row0, K, 0,  A0,    wv, lane); FENCE;
  stage_b128(Bt, col0, K, 64, B1, 0, wv, lane); FENCE;
  stage_b128(Bt, col0, K, 64, B1, 1, wv, lane); FENCE;
  asm volatile("s_waitcnt vmcnt(4)" ::: "memory");   // t0 fully landed (per-wave)
  __builtin_amdgcn_s_barrier();                      // all waves confirmed before reads

  const int nit = K >> 7;                 // iterations of 2 K-tiles
  for (int i = 0; i < nit; ++i) {
    const bool more = (i + 1 < nit);
    const int kA = i * 128 + 64;          // tile 2i+1
    const int kB = i * 128 + 128;         // tile 2i+2
    const int kC = i * 128 + 192;         // tile 2i+3
    { // ph1: read s0 (A-kc0 + B both kc); stage A(2i+1 -> s1)
      stage_a128(A, row0, K, kA, A1, wv, lane);
      short8 af[4];
#pragma unroll
      for (int m = 0; m < 4; ++m) af[m] = fragld128(A0, wr * 64 + m * 16 + mm, 0, quad);
#pragma unroll
      for (int j = 0; j < 4; ++j) {
        bfr[j][0] = fragld128(B0, wc * 64 + j * 16 + mm, 0, quad);
        bfr[j][1] = fragld128(B0, wc * 64 + j * 16 + mm, 1, quad);
      }
      __builtin_amdgcn_s_setprio(1);
#pragma unroll
      for (int m = 0; m < 4; ++m)
#pragma unroll
        for (int j = 0; j < 4; ++j)
          acc[m][j] = __builtin_amdgcn_mfma_f32_16x16x32_bf16(af[m], bfr[j][0], acc[m][j], 0, 0, 0);
      __builtin_amdgcn_s_setprio(0);
      asm volatile("s_waitcnt lgkmcnt(0)" ::: "memory");  // drain B-kc1 reads pre-overwrite
      __builtin_amdgcn_sched_barrier(0);
    }
    { // ph2: read s0 A-kc1; stage B(2i+2 -> s0); vmcnt confirms s1 for ph3
      __builtin_amdgcn_s_barrier();
      if (more) { stage_b128(Bt, col0, K, kB, B0, 0, wv, lane); FENCE;
                  stage_b128(Bt, col0, K, kB, B0, 1, wv, lane); FENCE; }
      if (more) { asm volatile("s_waitcnt vmcnt(4)" ::: "memory"); }
      else      { asm volatile("s_waitcnt vmcnt(0)" ::: "memory"); }
      short8 af[4];
#pragma unroll
      for (int m = 0; m < 4; ++m) af[m] = fragld128(A0, wr * 64 + m * 16 + mm, 1, quad);
      __builtin_amdgcn_s_setprio(1);
#pragma unroll
      for (int m = 0; m < 4; ++m)
#pragma unroll
        for (int j = 0; j < 4; ++j)
          acc[m][j] = __builtin_amdgcn_mfma_f32_16x16x32_bf16(af[m], bfr[j][1], acc[m][j], 0, 0, 0);
      __builtin_amdgcn_s_setprio(0);
    }
    { // ph3: read s1 (A-kc0 + B); stage A(2i+2 -> s0)
      __builtin_amdgcn_s_barrier();
      if (more) stage_a128(A, row0, K, kB, A0, wv, lane);
      short8 af[4];
#pragma unroll
      for (int m = 0; m < 4; ++m) af[m] = fragld128(A1, wr * 64 + m * 16 + mm, 0, quad);
#pragma unroll
      for (int j = 0; j < 4; ++j) {
        bfr[j][0] = fragld128(B1, wc * 64 + j * 16 + mm, 0, quad);
        bfr[j][1] = fragld128(B1, wc * 64 + j * 16 + mm, 1, quad);
      }
      __builtin_amdgcn_s_setprio(1);
#pragma unroll
      for (int m = 0; m < 4; ++m)
#pragma unroll
        for (int j = 0; j < 4; ++j)
          acc[m][j] = __builtin_amdgcn_mfma_f32_16x16x32_bf16(af[m], bfr[j][0], acc[m][j], 0, 0, 0);
      __builtin_amdgcn_s_setprio(0);
      asm volatile("s_waitcnt lgkmcnt(0)" ::: "memory");
      __builtin_amdgcn_sched_barrier(0);
    }
    { // ph4: read s1 A-kc1; stage B(2i+3 -> s1); vmcnt confirms s0 for next ph1
      __builtin_amdgcn_s_barrier();
      if (more) { stage_b128(Bt, col0, K, kC, B1, 0, wv, lane); FENCE;
                  stage_b128(Bt, col0, K, kC, B1, 1, wv, lane); FENCE;
                  asm volatile("s_waitcnt vmcnt(4)" ::: "memory"); }
      short8 af[4];
#pragma unroll
      for (int m = 0; m < 4; ++m) af[m] = fragld128(A1, wr * 64 + m * 16 + mm, 1, quad);
      __builtin_amdgcn_s_setprio(1);
#pragma unroll
      for (int m = 0; m < 4; ++m)
#pragma unroll
        for (int j = 0; j < 4; ++j)
          acc[m][j] = __builtin_amdgcn_mfma_f32_16x16x32_bf16(af[m], bfr[j][1], acc[m][j], 0, 0, 0);
      __builtin_amdgcn_s_setprio(0);
      __builtin_amdgcn_s_barrier();
    }
  }

  // epilogue: per-wave 64x64 at (row0 + wr*64, col0 + wc*64)
  if (mode == 0) {
#pragma unroll
    for (int m = 0; m < 4; ++m)
#pragma unroll
      for (int r = 0; r < 4; ++r) {
        const int row = row0 + wr * 64 + m * 16 + quad * 4 + r;
        float* cr = C + (size_t)row * N + col0 + wc * 64;
#pragma unroll
        for (int j = 0; j < 4; ++j) cr[j * 16 + mm] = acc[m][j][r];
      }
  } else {
    const int gcol = col0 + wc * 64;
    const int which = gcol >> 11;            // 0:q 1:k 2:v
    const int h = (gcol >> 7) & 15;
    const int coff = gcol & 127;
    ushort_t* dst = (which == 0) ? Qo : (which == 1) ? Ko : Vo;
#pragma unroll
    for (int m = 0; m < 4; ++m)
#pragma unroll
      for (int r = 0; r < 4; ++r) {
        const int row = row0 + wr * 64 + m * 16 + quad * 4 + r;
        const int bb = row >> 11, l = row & 2047;
        ushort_t* dr = dst + ((size_t)(bb * 16 + h) * 2048 + l) * 128 + coff;
#pragma unroll
        for (int j = 0; j < 4; ++j) dr[j * 16 + mm] = f2bf(acc[m][j][r]);
      }
  }
}

// ---------------------------------------------------------------- RoPE in-place on Q,K
__global__ __launch_bounds__(256) void rope_kernel(ushort_t* Qb, ushort_t* Kb) {
  const int gid = blockIdx.x * 256 + threadIdx.x;
  const int pd = gid & 63;
  const int row = gid >> 6;      // b*H*L + h*L + l
  const int l = row & 2047;
  ushort_t* base = (blockIdx.y ? Kb : Qb) + (size_t)row * 128;
  const float a = bf2f(base[pd]);
  const float bv = bf2f(base[pd + 64]);
  const float invf_rev = exp2f(-(float)pd * 0.20762050593045702f) * 0.15915494309189535f;
  float rev = (float)l * invf_rev;
  rev -= floorf(rev);
  const float ang = rev * 6.283185307179586f;
  float s, c;
  __sincosf(ang, &s, &c);
  float na = a * c - bv * s;
  float nb = bv * c + a * s;
  if (blockIdx.y == 0) { na *= 0.08838834764831845f; nb *= 0.08838834764831845f; }
  base[pd] = f2bf(na);
  base[pd + 64] = f2bf(nb);
}

// ---------------------------------------------------------------- V transpose per head
__global__ __launch_bounds__(256) void vtrans_kernel(const ushort_t* __restrict__ Vn,
                                                     ushort_t* __restrict__ Vt) {
  __shared__ ushort_t ls[128 * 132];
  const int bh = blockIdx.x >> 4;
  const int l0 = (blockIdx.x & 15) * 128;
  const int t = threadIdx.x;
  const ushort_t* src = Vn + ((size_t)bh * 2048 + l0) * 128;
#pragma unroll
  for (int it = 0; it < 16; ++it) {
    const int c = it * 256 + t;
    const int lr = c >> 5, dc = (c & 31) * 4;
    *(usvec4*)(ls + lr * 132 + dc) = *(const usvec4*)(src + lr * 128 + dc);
  }
  __syncthreads();
  ushort_t* dstb = Vt + (size_t)bh * 128 * 2048 + l0;
#pragma unroll
  for (int it = 0; it < 16; ++it) {
    const int c = it * 256 + t;
    const int d = c >> 5, lc = (c & 31) * 4;
    usvec4 o;
    o[0] = ls[(lc + 0) * 132 + d];
    o[1] = ls[(lc + 1) * 132 + d];
    o[2] = ls[(lc + 2) * 132 + d];
    o[3] = ls[(lc + 3) * 132 + d];
    *(usvec4*)(dstb + (size_t)d * 2048 + lc) = o;
  }
}

// ---------------------------------------------------------------- flash attention v2
// Round-4 changes: (1) per-tile blocking am-load+ballot replaced with a one-time
// 4-ballot precompute of per-tile mask-fullness bits (slow path only for tiles
// with actual padding); (2) QK sacc chain split into two 4-deep chains.
__global__ __launch_bounds__(256, 2) void flash_kernel(
    const ushort_t* __restrict__ Qb, const ushort_t* __restrict__ Kb,
    const ushort_t* __restrict__ Vt, const int* __restrict__ am,
    ushort_t* __restrict__ Y) {
  __shared__ __align__(16) ushort_t lK[2][8192];
  __shared__ __align__(16) ushort_t lV[2][8192];
  __shared__ float lds_l[128];

  const int tid = threadIdx.x, wv = tid >> 6, lane = tid & 63;
  const int lh = lane >> 5, cq = lane & 31;
  const int bid = blockIdx.x;
  const int bh = bid & 31;
  const int qi = 15 - (bid >> 5);
  const int b = bh >> 4, head = bh & 15;
  const size_t qkBase = (size_t)bh * (2048 * 128);
  const int qb = qi * 128 + wv * 32;
  const int q = qb + cq;

  // one-time mask-fullness bits: bit t = all 64 keys of tile t unmasked
  unsigned fullbits = 0;
  {
    const int* amr = am + b * 2048;
#pragma unroll
    for (int rgn = 0; rgn < 4; ++rgn) {
      const int4 a0 = *(const int4*)(amr + rgn * 512 + lane * 8);
      const int4 a1 = *(const int4*)(amr + rgn * 512 + lane * 8 + 4);
      const bool ok8 = a0.x && a0.y && a0.z && a0.w && a1.x && a1.y && a1.z && a1.w;
      const unsigned long long bal = __ballot(ok8);
#pragma unroll
      for (int tt = 0; tt < 8; ++tt)
        fullbits |= ((((bal >> (8 * tt)) & 0xFFull) == 0xFFull) ? 1u : 0u) << (rgn * 8 + tt);
    }
  }

  short8 qf[8];
  {
    const ushort_t* qrow = Qb + qkBase + (size_t)q * 128;
#pragma unroll
    for (int c = 0; c < 8; ++c) qf[c] = *(const short8*)(qrow + c * 16 + lh * 8);
  }

  fvec16 yacc[4];
#pragma unroll
  for (int i = 0; i < 4; ++i)
#pragma unroll
    for (int r = 0; r < 16; ++r) yacc[i][r] = 0.f;
  float psum = 0.f;

#define FLASH_STAGE(dK, dV, kk0)                                                          \
  _Pragma("unroll")                                                                       \
  for (int it = 0; it < 4; ++it) {                                                        \
    const int f_ = it * 4 + wv;                                                           \
    const int ct_ = f_ >> 3, c_ = f_ & 7;                                                 \
    glds16(Kb + qkBase + (size_t)((kk0) + ct_ * 32 + cq) * 128 + c_ * 16 + lh * 8,        \
           (dK) + f_ * 512);                                                              \
    const int dt_ = f_ >> 2, kc_ = f_ & 3;                                                \
    glds16(Vt + ((size_t)bh * 128 + dt_ * 32 + cq) * 2048 + (kk0) + kc_ * 16 + lh * 8,    \
           (dV) + f_ * 512);                                                              \
  }

  const int nt = qi * 2 + 2;
  FLASH_STAGE(&lK[0][0], &lV[0][0], 0)
  __syncthreads();

  int cur = 0;
  for (int t = 0; t < nt; ++t) {
    const int k0 = t * 64;
    if (t + 1 < nt) {
      FLASH_STAGE(&lK[cur ^ 1][0], &lV[cur ^ 1][0], k0 + 64)
    }

    if (k0 <= qb + 31) {
      const ushort_t* bK = &lK[cur][0];
      const ushort_t* bV = &lV[cur][0];
      const bool maskfull = (fullbits >> t) & 1u;
      unsigned long long keymask = ~0ull;
      if (!maskfull) keymask = __ballot(am[b * 2048 + k0 + lane] != 0);
      const bool fullvalid = (k0 + 63 <= qb) && maskfull;

#pragma unroll
      for (int ct = 0; ct < 2; ++ct) {
        fvec16 sA_, sB_;
#pragma unroll
        for (int r = 0; r < 16; ++r) { sA_[r] = 0.f; sB_[r] = 0.f; }
        __builtin_amdgcn_s_setprio(1);
#pragma unroll
        for (int c = 0; c < 4; ++c) {
          short8 kf = *(const short8*)(bK + (ct * 8 + c) * 512 + lane * 8);
          sA_ = __builtin_amdgcn_mfma_f32_32x32x16_bf16(kf, qf[c], sA_, 0, 0, 0);
        }
#pragma unroll
        for (int c = 4; c < 8; ++c) {
          short8 kf = *(const short8*)(bK + (ct * 8 + c) * 512 + lane * 8);
          sB_ = __builtin_amdgcn_mfma_f32_32x32x16_bf16(kf, qf[c], sB_, 0, 0, 0);
        }
        __builtin_amdgcn_s_setprio(0);
        // S^T C-layout: value r is S[q][key], key = (r&3)+8*(r>>2)+4*lh (+ct*32+k0)
        float p[16];
        if (fullvalid) {
#pragma unroll
          for (int r = 0; r < 16; ++r) p[r] = __expf(sA_[r] + sB_[r]);
        } else {
#pragma unroll
          for (int r = 0; r < 16; ++r) {
            const int kl = (r & 3) + 8 * (r >> 2) + 4 * lh + ct * 32;
            const bool ok = (k0 + kl <= q) && (((keymask >> kl) & 1ull) != 0);
            p[r] = ok ? __expf(sA_[r] + sB_[r]) : 0.f;
          }
        }
#pragma unroll
        for (int r = 0; r < 16; ++r) psum += p[r];
        unsigned pk[8];
#pragma unroll
        for (int j = 0; j < 8; ++j) {
          __hip_bfloat162 t2 = __float22bfloat162_rn(make_float2(p[2 * j], p[2 * j + 1]));
          pk[j] = *(unsigned*)&t2;
        }
#pragma unroll
        for (int kc2 = 0; kc2 < 2; ++kc2) {
          unsigned a0 = pk[kc2 * 4 + 0], a2 = pk[kc2 * 4 + 2];
          unsigned a1 = pk[kc2 * 4 + 1], a3 = pk[kc2 * 4 + 3];
          swap32(a0, a2);
          swap32(a1, a3);
          union { unsigned u[4]; short8 s; } pf;
          pf.u[0] = a0; pf.u[1] = a1; pf.u[2] = a2; pf.u[3] = a3;
          const int kc = ct * 2 + kc2;
          __builtin_amdgcn_s_setprio(1);
#pragma unroll
          for (int dt = 0; dt < 4; ++dt) {
            short8 vf = *(const short8*)(bV + (dt * 4 + kc) * 512 + lane * 8);
            yacc[dt] = __builtin_amdgcn_mfma_f32_32x32x16_bf16(pf.s, vf, yacc[dt], 0, 0, 0);
          }
          __builtin_amdgcn_s_setprio(0);
        }
      }
    }
    __syncthreads();
    cur ^= 1;
  }
#undef FLASH_STAGE

  psum += __shfl_xor(psum, 32);
  if (lane < 32) lds_l[wv * 32 + lane] = psum;
  float inv16[16];
#pragma unroll
  for (int r = 0; r < 16; ++r)
    inv16[r] = 1.f / lds_l[wv * 32 + (r & 3) + 8 * (r >> 2) + 4 * lh];

#pragma unroll
  for (int dt = 0; dt < 4; ++dt)
#pragma unroll
    for (int r = 0; r < 16; ++r) {
      const int qloc = (r & 3) + 8 * (r >> 2) + 4 * lh;
      ushort_t* dst = Y + ((size_t)(b * 2048 + qb + qloc)) * 2048 + head * 128 + dt * 32 + cq;
      *dst = f2bf(yacc[dt][r] * inv16[r]);
    }
}

// ---------------------------------------------------------------- launch
extern "C" void kernel_launch(void* const* d_in, const int* in_sizes, int n_in,
                              void* d_out, int out_size, void* d_ws, size_t ws_size,
                              hipStream_t stream) {
  const float* x      = (const float*)d_in[0];
  const int*   amask  = (const int*)d_in[1];
  const float* w_qkv  = (const float*)d_in[2];
  const float* w_proj = (const float*)d_in[3];

  ushort_t* xb     = (ushort_t*)d_ws;          // 8,388,608   (dead after gemm1)
  ushort_t* wqkvT  = xb + 8388608;             // 12,582,912  (dead after gemm1)
  ushort_t* wprojT = wqkvT + 12582912;         // 4,194,304
  ushort_t* Qb     = wprojT + 4194304;         // 8,388,608
  ushort_t* Kb     = Qb + 8388608;             // 8,388,608
  ushort_t* Vn     = Kb + 8388608;             // 8,388,608  -> total 96 MiB
  ushort_t* Vt     = wqkvT;                    // reuse
  ushort_t* Yb     = xb;                       // reuse

  cast_f32_bf16<<<8192, 256, 0, stream>>>(x, xb);
  tcast<<<dim3(96, 32), 256, 0, stream>>>(w_qkv, wqkvT, 2048, 6144);
  tcast<<<dim3(32, 32), 256, 0, stream>>>(w_proj, wprojT, 2048, 2048);
  gemm128<<<768, 512, 0, stream>>>(xb, wqkvT, 4096, 6144, 2048, 1,
                                   nullptr, Qb, Kb, Vn);
  rope_kernel<<<dim3(16384, 2), 256, 0, stream>>>(Qb, Kb);
  vtrans_kernel<<<512, 256, 0, stream>>>(Vn, Vt);
  flash_kernel<<<512, 256, 0, stream>>>(Qb, Kb, Vt, amask, Yb);
  gemm128<<<256, 512, 0, stream>>>(Yb, wprojT, 4096, 2048, 2048, 0,
                                   (float*)d_out, nullptr, nullptr, nullptr);
}

// Round 5
// 383.064 us; speedup vs baseline: 1.2987x; 1.0200x over previous
//
#include <hip/hip_runtime.h>
#include <hip/hip_bf16.h>

// Problem constants: B=2, L=2048, D=2048, H=16, Dh=128, 3D=6144
typedef unsigned short ushort_t;
typedef __attribute__((ext_vector_type(4))) float fvec4;
typedef __attribute__((ext_vector_type(16))) float fvec16;
typedef __attribute__((ext_vector_type(8))) short short8;   // 8 bf16 (4 VGPRs) - MFMA A/B frag
typedef __attribute__((ext_vector_type(4))) unsigned short usvec4;
typedef __attribute__((ext_vector_type(2))) unsigned int uvec2;

typedef const __attribute__((address_space(1))) void* gas_ptr;
typedef __attribute__((address_space(3))) void* las_ptr;

__device__ __forceinline__ void glds16(const void* g, void* l) {
  // async global->LDS, 16B/lane, LDS dest = wave-uniform base + lane*16
  __builtin_amdgcn_global_load_lds((gas_ptr)g, (las_ptr)l, 16, 0, 0);
}

__device__ __forceinline__ ushort_t f2bf(float f) {
  unsigned u = __float_as_uint(f);
  u += 0x7FFFu + ((u >> 16) & 1u);   // RNE
  return (ushort_t)(u >> 16);
}
__device__ __forceinline__ float bf2f(ushort_t h) {
  return __uint_as_float(((unsigned)h) << 16);
}

// permlane32_swap: a' = [a.lo32lanes, b.lo32lanes], b' = [a.hi, b.hi]
__device__ __forceinline__ void swap32(unsigned& a, unsigned& b) {
#if __has_builtin(__builtin_amdgcn_permlane32_swap)
  uvec2 r = __builtin_amdgcn_permlane32_swap(a, b, false, false);
  a = r[0]; b = r[1];
#else
  const unsigned sa = (unsigned)__shfl_xor((int)a, 32);
  const unsigned sb = (unsigned)__shfl_xor((int)b, 32);
  const bool hi = (threadIdx.x & 32) != 0;
  const unsigned na = hi ? sb : a;
  const unsigned nb = hi ? b : sa;
  a = na; b = nb;
#endif
}

// ---------------------------------------------------------------- cast x -> bf16
__global__ __launch_bounds__(256) void cast_f32_bf16(const float* __restrict__ X,
                                                     ushort_t* __restrict__ Xb) {
  const size_t i = ((size_t)blockIdx.x * 256 + threadIdx.x) * 4;
  const fvec4 v = *(const fvec4*)(X + i);
  usvec4 o;
  o[0] = f2bf(v[0]); o[1] = f2bf(v[1]); o[2] = f2bf(v[2]); o[3] = f2bf(v[3]);
  *(usvec4*)(Xb + i) = o;
}

// ------------------------------------- transpose+cast weights: W(Kd,Nd) -> Wt(Nd,Kd) bf16
__global__ __launch_bounds__(256) void tcast(const float* __restrict__ W,
                                             ushort_t* __restrict__ Wt,
                                             const int Kd, const int Nd) {
  __shared__ float ls[64][65];
  const int t = threadIdx.x;
  const int n0 = blockIdx.x * 64, k0 = blockIdx.y * 64;
  const int kr = t >> 4, nc = (t & 15) * 4;
#pragma unroll
  for (int it = 0; it < 4; ++it) {
    const fvec4 v = *(const fvec4*)(W + (size_t)(k0 + it * 16 + kr) * Nd + n0 + nc);
    ls[it * 16 + kr][nc + 0] = v[0];
    ls[it * 16 + kr][nc + 1] = v[1];
    ls[it * 16 + kr][nc + 2] = v[2];
    ls[it * 16 + kr][nc + 3] = v[3];
  }
  __syncthreads();
  const int nr = t >> 2, kg = (t & 3) * 16;
  __align__(16) ushort_t tmp[16];
#pragma unroll
  for (int i = 0; i < 16; ++i) tmp[i] = f2bf(ls[kg + i][nr]);
  ushort_t* dst = Wt + (size_t)(n0 + nr) * Kd + k0 + kg;
  *(short8*)(dst)     = *(const short8*)(tmp);
  *(short8*)(dst + 8) = *(const short8*)(tmp + 8);
}

#define FENCE asm volatile("" ::: "memory")

// ---------------- shared GEMM helpers (T2 swizzle: pre-swizzled global k-chunk;
// reads XOR (row&7)<<4 into the 16B-slot bits; LDS row = 64 ushorts = 128 B)
__device__ __forceinline__ void stage_one(const ushort_t* __restrict__ G, const int grow,
                                          const int K, const int tk, ushort_t* ldsmat,
                                          const int lrow0, const int wv, const int lane) {
  const int rr = lane >> 3;                     // row within 8-row group (= row&7 of global)
  const int kk = ((lane & 7) ^ rr) * 8;         // pre-swizzled global k-chunk (ushorts)
  glds16(G + (size_t)(grow + wv * 8 + rr) * K + tk + kk,
         ldsmat + (lrow0 + wv * 8) * 64);
}

// A-frag read with {0,1,2,3}->{0,2,1,3} 64-row block permute (gemm192 A only)
__device__ __forceinline__ short8 frag_ld(const ushort_t* ldsmat, const int rbase,
                                          const int kc, const int quad, const int mm) {
  const int r = rbase + mm;                     // global row within tile
  const int blk = r >> 6;
  const int pblk = ((blk & 1) << 1) | (blk >> 1);   // {0,1,2,3}->{0,2,1,3}
  const int ldsrow = pblk * 64 + (r & 63);
  const int kb = (kc * 64 + quad * 16) ^ ((mm & 7) << 4);   // swizzled byte-in-row
  return *(const short8*)(ldsmat + ldsrow * 64 + (kb >> 1));
}

// identity-layout frag read (gemm128 A/B, gemm192 B)
__device__ __forceinline__ short8 fragld128(const ushort_t* mat, const int row,
                                            const int kc, const int quad) {
  const int kb = (kc * 64 + quad * 16) ^ ((row & 7) << 4);
  return *(const short8*)(mat + row * 64 + (kb >> 1));
}

// ================================================================ 256x192 8-phase GEMM
// C(M,N) = A(M,K) * Bt(N,K)^T.  BM=256, BN=192, BK=64, 512 thr = 8 waves (2M x 4N),
// per-wave output 128x48 (acc[8][3]).  LDS 112 KiB: [slot2][ A 256x64 | B 192x64 ].
//
// Grid quantization: QKV = (4096/256)x(6144/192) = 16x32 = 512 blocks = 2 EXACT
// rounds at 1 block/CU (gemm256's 384 blocks cost 2 rounds with a half-idle 2nd).
//
// A row placement: global 64-row block g stored at lds offset {0,128,64,192}[g]
// (the {0,2,1,3} permute) so lds rows 0-127 are read ph1-2 and rows 128-255 are
// read ph3-4 of the slot's half-iteration -> staged regions trail their readers
// by >=1 barrier.  B identity (192 rows), fully read at ph1/ph5 -> overwrite
// from ph2/ph6 on is safe.
//
// Staging: single-glds 64-row units.  Per iteration (tiles 2i->s0, 2i+1->s1),
// 14 glds:
//  ph1: rd s0 B(6)+A-q0 | stage c1,c3(2i+1)->s1@128,192
//  ph2: rd s0 A-q1      | stage b0,b1(2i+2)->s0
//  ph3: rd s0 A-q2      | stage b2(2i+2)->s0
//  ph4: rd s0 A-q3      | stage c0,c2(2i+2)->s0@0,64   vmcnt(5)
//  ph5: rd s1 B(6)+A-q0 | stage c1,c3(2i+2)->s0@128,192
//  ph6: rd s1 A-q1      | stage b0,b1(2i+3)->s1
//  ph7: rd s1 A-q2      | stage b2(2i+3)->s1
//  ph8: rd s1 A-q3      | stage c0,c2(2i+3)->s1@0,64   vmcnt(5)
// vmcnt ledger: ph4's vmcnt(5) leaves newest 5 (ph2:2,ph3:1,ph4:2) in flight ->
// confirms prev ph6,7,8 + cur ph1 = tile 2i+1 complete before ph5 reads it.
// ph8's vmcnt(5) leaves ph6:2,ph7:1,ph8:2 -> confirms ph2..ph5 = tile 2i+2
// complete before next ph1.  Prologue: tile0 (7 glds) + tile1 b*,c0,c2 (5),
// vmcnt(5) confirms tile0; tile1 floaters confirmed at iter-0 ph4.
// Tail (i=nit-1): ph1 still stages c1,c3 (last tile); ph4 uses vmcnt(0).
// WAR (one barrier per phase, reads after barrier, stage after reads):
// every staged region's last reader is >=1 barrier earlier (listed above);
// cross-wave safe because readers consume ds_reads via MFMA before the barrier.
#define G192_LDA(Am, q_)                                                      \
  short8 af[2][2];                                                            \
  af[0][0] = frag_ld(Am, wr * 128 + (q_) * 32,      0, quad, mm);             \
  af[0][1] = frag_ld(Am, wr * 128 + (q_) * 32,      1, quad, mm);             \
  af[1][0] = frag_ld(Am, wr * 128 + (q_) * 32 + 16, 0, quad, mm);             \
  af[1][1] = frag_ld(Am, wr * 128 + (q_) * 32 + 16, 1, quad, mm);

#define G192_LDB(Bm)                                                          \
  _Pragma("unroll")                                                           \
  for (int j = 0; j < 3; ++j) {                                               \
    bfr[j][0] = fragld128(Bm, wc * 48 + j * 16 + mm, 0, quad);                \
    bfr[j][1] = fragld128(Bm, wc * 48 + j * 16 + mm, 1, quad);                \
  }

#define G192_MFMA(q_)                                                         \
  __builtin_amdgcn_s_setprio(1);                                              \
  _Pragma("unroll")                                                           \
  for (int ii = 0; ii < 2; ++ii)                                              \
  _Pragma("unroll")                                                           \
  for (int j = 0; j < 3; ++j) {                                               \
    acc[(q_) * 2 + ii][j] = __builtin_amdgcn_mfma_f32_16x16x32_bf16(          \
        af[ii][0], bfr[j][0], acc[(q_) * 2 + ii][j], 0, 0, 0);                \
    acc[(q_) * 2 + ii][j] = __builtin_amdgcn_mfma_f32_16x16x32_bf16(          \
        af[ii][1], bfr[j][1], acc[(q_) * 2 + ii][j], 0, 0, 0);                \
  }                                                                           \
  __builtin_amdgcn_s_setprio(0);

__global__ __launch_bounds__(512, 2) void gemm192(
    const ushort_t* __restrict__ A, const ushort_t* __restrict__ Bt,
    const int M, const int N, const int K, const int mode,
    float* __restrict__ C,
    ushort_t* __restrict__ Qo, ushort_t* __restrict__ Ko, ushort_t* __restrict__ Vo) {
  __shared__ __align__(16) ushort_t lds[2][28672];   // per slot: A[0..16383], B[16384..28671]

  const int tid = threadIdx.x, wv = tid >> 6, lane = tid & 63;
  const int quad = lane >> 4, mm = lane & 15;
  const int wr = wv >> 2, wc = wv & 3;   // 2M x 4N

  const int nwg = gridDim.x, ntx = N / 192;
  const int bid = blockIdx.x;
  const int swz = (bid & 7) * (nwg >> 3) + (bid >> 3);
  const int by = swz / ntx, bx = swz - by * ntx;
  const int row0 = by * 256, col0 = bx * 192;

  fvec4 acc[8][3];
#pragma unroll
  for (int i = 0; i < 8; ++i)
#pragma unroll
    for (int j = 0; j < 3; ++j) acc[i][j] = (fvec4){0.f, 0.f, 0.f, 0.f};

  short8 bfr[3][2];

  ushort_t* A0 = &lds[0][0];      ushort_t* B0 = &lds[0][16384];
  ushort_t* A1 = &lds[1][0];      ushort_t* B1 = &lds[1][16384];

  // ---- prologue: tile0 {b0,b1,b2,c0,c1,c2,c3} + tile1 {b0,b1,b2,c0,c2} = 12 glds
  stage_one(Bt, col0 + 0,   K, 0,  B0, 0,   wv, lane); FENCE;
  stage_one(Bt, col0 + 64,  K, 0,  B0, 64,  wv, lane); FENCE;
  stage_one(Bt, col0 + 128, K, 0,  B0, 128, wv, lane); FENCE;
  stage_one(A,  row0 + 0,   K, 0,  A0, 0,   wv, lane); FENCE;
  stage_one(A,  row0 + 64,  K, 0,  A0, 128, wv, lane); FENCE;   // c1 -> pblk 2
  stage_one(A,  row0 + 128, K, 0,  A0, 64,  wv, lane); FENCE;   // c2 -> pblk 1
  stage_one(A,  row0 + 192, K, 0,  A0, 192, wv, lane); FENCE;
  stage_one(Bt, col0 + 0,   K, 64, B1, 0,   wv, lane); FENCE;
  stage_one(Bt, col0 + 64,  K, 64, B1, 64,  wv, lane); FENCE;
  stage_one(Bt, col0 + 128, K, 64, B1, 128, wv, lane); FENCE;
  stage_one(A,  row0 + 0,   K, 64, A1, 0,   wv, lane); FENCE;
  stage_one(A,  row0 + 128, K, 64, A1, 64,  wv, lane); FENCE;
  asm volatile("s_waitcnt vmcnt(5)" ::: "memory");   // tile0 landed; tile1's 5 float
  __builtin_amdgcn_s_barrier();

  const int nit = K >> 7;                 // iterations of 2 K-tiles
  for (int i = 0; i < nit; ++i) {
    const bool more = (i + 1 < nit);
    const int kA = i * 128 + 64;          // tile 2i+1
    const int kB = i * 128 + 128;         // tile 2i+2
    const int kC = i * 128 + 192;         // tile 2i+3
    { // ph1
      __builtin_amdgcn_s_barrier();
      G192_LDA(A0, 0);
      G192_LDB(B0);
      stage_one(A, row0 + 64,  K, kA, A1, 128, wv, lane); FENCE;
      stage_one(A, row0 + 192, K, kA, A1, 192, wv, lane);
      G192_MFMA(0);
    }
    { // ph2
      __builtin_amdgcn_s_barrier();
      G192_LDA(A0, 1);
      if (more) { stage_one(Bt, col0 + 0,  K, kB, B0, 0,  wv, lane); FENCE;
                  stage_one(Bt, col0 + 64, K, kB, B0, 64, wv, lane); }
      G192_MFMA(1);
    }
    { // ph3
      __builtin_amdgcn_s_barrier();
      G192_LDA(A0, 2);
      if (more) stage_one(Bt, col0 + 128, K, kB, B0, 128, wv, lane);
      G192_MFMA(2);
    }
    { // ph4
      __builtin_amdgcn_s_barrier();
      G192_LDA(A0, 3);
      if (more) {
        stage_one(A, row0 + 0,   K, kB, A0, 0,  wv, lane); FENCE;
        stage_one(A, row0 + 128, K, kB, A0, 64, wv, lane);
        asm volatile("s_waitcnt vmcnt(5)" ::: "memory");
      } else {
        asm volatile("s_waitcnt vmcnt(0)" ::: "memory");
      }
      G192_MFMA(3);
    }
    { // ph5
      __builtin_amdgcn_s_barrier();
      G192_LDA(A1, 0);
      G192_LDB(B1);
      if (more) { stage_one(A, row0 + 64,  K, kB, A0, 128, wv, lane); FENCE;
                  stage_one(A, row0 + 192, K, kB, A0, 192, wv, lane); }
      G192_MFMA(0);
    }
    { // ph6
      __builtin_amdgcn_s_barrier();
      G192_LDA(A1, 1);
      if (more) { stage_one(Bt, col0 + 0,  K, kC, B1, 0,  wv, lane); FENCE;
                  stage_one(Bt, col0 + 64, K, kC, B1, 64, wv, lane); }
      G192_MFMA(1);
    }
    { // ph7
      __builtin_amdgcn_s_barrier();
      G192_LDA(A1, 2);
      if (more) stage_one(Bt, col0 + 128, K, kC, B1, 128, wv, lane);
      G192_MFMA(2);
    }
    { // ph8
      __builtin_amdgcn_s_barrier();
      G192_LDA(A1, 3);
      if (more) {
        stage_one(A, row0 + 0,   K, kC, A1, 0,  wv, lane); FENCE;
        stage_one(A, row0 + 128, K, kC, A1, 64, wv, lane);
        asm volatile("s_waitcnt vmcnt(5)" ::: "memory");
      }
      G192_MFMA(3);
    }
  }

  // ---- epilogue: per-wave 128 rows x 48 cols at (row0 + wr*128, col0 + wc*48)
  if (mode == 0) {
#pragma unroll
    for (int i = 0; i < 8; ++i)
#pragma unroll
      for (int r = 0; r < 4; ++r) {
        const int row = row0 + wr * 128 + i * 16 + quad * 4 + r;
        float* cr = C + (size_t)row * N + col0 + wc * 48;
#pragma unroll
        for (int j = 0; j < 3; ++j) cr[j * 16 + mm] = acc[i][j][r];
      }
  } else {
#pragma unroll
    for (int j = 0; j < 3; ++j) {
      const int gcolj = col0 + wc * 48 + j * 16;   // 16-aligned: one head per j-block
      const int which = gcolj >> 11;               // 0:q 1:k 2:v
      const int h = (gcolj >> 7) & 15;
      const int coff = (gcolj & 127) + mm;
      ushort_t* dst = (which == 0) ? Qo : (which == 1) ? Ko : Vo;
#pragma unroll
      for (int i = 0; i < 8; ++i)
#pragma unroll
        for (int r = 0; r < 4; ++r) {
          const int row = row0 + wr * 128 + i * 16 + quad * 4 + r;
          const int bb = row >> 11, l = row & 2047;
          dst[((size_t)(bb * 16 + h) * 2048 + l) * 128 + coff] = f2bf(acc[i][j][r]);
        }
    }
  }
}

// ================================================================ 128x256 4-phase GEMM
// (proj: 32x8 = 256 blocks = 1 exact round; proven round-4 kernel, unchanged)
__device__ __forceinline__ void stage_a128(const ushort_t* __restrict__ G, const int row0,
                                           const int K, const int tk, ushort_t* ldsA,
                                           const int wv, const int lane) {
  const int rr = lane >> 3;
  const int kk = ((lane & 7) ^ rr) * 8;
  const int r = wv * 8 + rr;
  glds16(G + (size_t)(row0 + r) * K + tk + kk,      ldsA + (wv * 8) * 64);
  glds16(G + (size_t)(row0 + 64 + r) * K + tk + kk, ldsA + (64 + wv * 8) * 64);
}
__device__ __forceinline__ void stage_b128(const ushort_t* __restrict__ G, const int col0,
                                           const int K, const int tk, ushort_t* ldsB,
                                           const int u, const int wv, const int lane) {
  const int rr = lane >> 3;
  const int kk = ((lane & 7) ^ rr) * 8;
  const int r = u * 64 + wv * 8 + rr;
  glds16(G + (size_t)(col0 + r) * K + tk + kk,       ldsB + (u * 64 + wv * 8) * 64);
  glds16(G + (size_t)(col0 + 128 + r) * K + tk + kk, ldsB + (128 + u * 64 + wv * 8) * 64);
}

__global__ __launch_bounds__(512, 2) void gemm128(
    const ushort_t* __restrict__ A, const ushort_t* __restrict__ Bt,
    const int M, const int N, const int K, const int mode,
    float* __restrict__ C,
    ushort_t* __restrict__ Qo, ushort_t* __restrict__ Ko, ushort_t* __restrict__ Vo) {
  __shared__ __align__(16) ushort_t l128[2][24576];   // per slot: A[0..8191], B[8192..24575]

  const int tid = threadIdx.x, wv = tid >> 6, lane = tid & 63;
  const int quad = lane >> 4, mm = lane & 15;
  const int wr = wv >> 2, wc = wv & 3;   // 2M x 4N

  const int nwg = gridDim.x, ntx = N >> 8;
  const int bid = blockIdx.x;
  const int swz = (bid & 7) * (nwg >> 3) + (bid >> 3);
  const int by = swz / ntx, bx = swz - by * ntx;
  const int row0 = by * 128, col0 = bx * 256;

  fvec4 acc[4][4];
#pragma unroll
  for (int m = 0; m < 4; ++m)
#pragma unroll
    for (int j = 0; j < 4; ++j) acc[m][j] = (fvec4){0.f, 0.f, 0.f, 0.f};

  ushort_t* A0 = &l128[0][0];     ushort_t* B0 = &l128[0][8192];
  ushort_t* A1 = &l128[1][0];     ushort_t* B1 = &l128[1][8192];

  short8 bfr[4][2];

  stage_b128(Bt, col0, K, 0,  B0, 0, wv, lane); FENCE;
  stage_b128(Bt, col0, K, 0,  B0, 1, wv, lane); FENCE;
  stage_a128(A,  row0, K, 0,  A0,    wv, lane); FENCE;
  stage_b128(Bt, col0, K, 64, B1, 0, wv, lane); FENCE;
  stage_b128(Bt, col0, K, 64, B1, 1, wv, lane); FENCE;
  asm volatile("s_waitcnt vmcnt(4)" ::: "memory");
  __builtin_amdgcn_s_barrier();

  const int nit = K >> 7;
  for (int i = 0; i < nit; ++i) {
    const bool more = (i + 1 < nit);
    const int kA = i * 128 + 64;
    const int kB = i * 128 + 128;
    const int kC = i * 128 + 192;
    { // ph1
      stage_a128(A, row0, K, kA, A1, wv, lane);
      short8 af[4];
#pragma unroll
      for (int m = 0; m < 4; ++m) af[m] = fragld128(A0, wr * 64 + m * 16 + mm, 0, quad);
#pragma unroll
      for (int j = 0; j < 4; ++j) {
        bfr[j][0] = fragld128(B0, wc * 64 + j * 16 + mm, 0, quad);
        bfr[j][1] = fragld128(B0, wc * 64 + j * 16 + mm, 1, quad);
      }
      __builtin_amdgcn_s_setprio(1);
#pragma unroll
      for (int m = 0; m < 4; ++m)
#pragma unroll
        for (int j = 0; j < 4; ++j)
          acc[m][j] = __builtin_amdgcn_mfma_f32_16x16x32_bf16(af[m], bfr[j][0], acc[m][j], 0, 0, 0);
      __builtin_amdgcn_s_setprio(0);
      asm volatile("s_waitcnt lgkmcnt(0)" ::: "memory");
      __builtin_amdgcn_sched_barrier(0);
    }
    { // ph2
      __builtin_amdgcn_s_barrier();
      if (more) { stage_b128(Bt, col0, K, kB, B0, 0, wv, lane); FENCE;
                  stage_b128(Bt, col0, K, kB, B0, 1, wv, lane); FENCE; }
      if (more) { asm volatile("s_waitcnt vmcnt(4)" ::: "memory"); }
      else      { asm volatile("s_waitcnt vmcnt(0)" ::: "memory"); }
      short8 af[4];
#pragma unroll
      for (int m = 0; m < 4; ++m) af[m] = fragld128(A0, wr * 64 + m * 16 + mm, 1, quad);
      __builtin_amdgcn_s_setprio(1);
#pragma unroll
      for (int m = 0; m < 4; ++m)
#pragma unroll
        for (int j = 0; j < 4; ++j)
          acc[m][j] = __builtin_amdgcn_mfma_f32_16x16x32_bf16(af[m], bfr[j][1], acc[m][j], 0, 0, 0);
      __builtin_amdgcn_s_setprio(0);
    }
    { // ph3
      __builtin_amdgcn_s_barrier();
      if (more) stage_a128(A, row0, K, kB, A0, wv, lane);
      short8 af[4];
#pragma unroll
      for (int m = 0; m < 4; ++m) af[m] = fragld128(A1, wr * 64 + m * 16 + mm, 0, quad);
#pragma unroll
      for (int j = 0; j < 4; ++j) {
        bfr[j][0] = fragld128(B1, wc * 64 + j * 16 + mm, 0, quad);
        bfr[j][1] = fragld128(B1, wc * 64 + j * 16 + mm, 1, quad);
      }
      __builtin_amdgcn_s_setprio(1);
#pragma unroll
      for (int m = 0; m < 4; ++m)
#pragma unroll
        for (int j = 0; j < 4; ++j)
          acc[m][j] = __builtin_amdgcn_mfma_f32_16x16x32_bf16(af[m], bfr[j][0], acc[m][j], 0, 0, 0);
      __builtin_amdgcn_s_setprio(0);
      asm volatile("s_waitcnt lgkmcnt(0)" ::: "memory");
      __builtin_amdgcn_sched_barrier(0);
    }
    { // ph4
      __builtin_amdgcn_s_barrier();
      if (more) { stage_b128(Bt, col0, K, kC, B1, 0, wv, lane); FENCE;
                  stage_b128(Bt, col0, K, kC, B1, 1, wv, lane); FENCE;
                  asm volatile("s_waitcnt vmcnt(4)" ::: "memory"); }
      short8 af[4];
#pragma unroll
      for (int m = 0; m < 4; ++m) af[m] = fragld128(A1, wr * 64 + m * 16 + mm, 1, quad);
      __builtin_amdgcn_s_setprio(1);
#pragma unroll
      for (int m = 0; m < 4; ++m)
#pragma unroll
        for (int j = 0; j < 4; ++j)
          acc[m][j] = __builtin_amdgcn_mfma_f32_16x16x32_bf16(af[m], bfr[j][1], acc[m][j], 0, 0, 0);
      __builtin_amdgcn_s_setprio(0);
      __builtin_amdgcn_s_barrier();
    }
  }

  if (mode == 0) {
#pragma unroll
    for (int m = 0; m < 4; ++m)
#pragma unroll
      for (int r = 0; r < 4; ++r) {
        const int row = row0 + wr * 64 + m * 16 + quad * 4 + r;
        float* cr = C + (size_t)row * N + col0 + wc * 64;
#pragma unroll
        for (int j = 0; j < 4; ++j) cr[j * 16 + mm] = acc[m][j][r];
      }
  } else {
    const int gcol = col0 + wc * 64;
    const int which = gcol >> 11;
    const int h = (gcol >> 7) & 15;
    const int coff = gcol & 127;
    ushort_t* dst = (which == 0) ? Qo : (which == 1) ? Ko : Vo;
#pragma unroll
    for (int m = 0; m < 4; ++m)
#pragma unroll
      for (int r = 0; r < 4; ++r) {
        const int row = row0 + wr * 64 + m * 16 + quad * 4 + r;
        const int bb = row >> 11, l = row & 2047;
        ushort_t* dr = dst + ((size_t)(bb * 16 + h) * 2048 + l) * 128 + coff;
#pragma unroll
        for (int j = 0; j < 4; ++j) dr[j * 16 + mm] = f2bf(acc[m][j][r]);
      }
  }
}

// ---------------------------------------------------------------- RoPE in-place on Q,K
__global__ __launch_bounds__(256) void rope_kernel(ushort_t* Qb, ushort_t* Kb) {
  const int gid = blockIdx.x * 256 + threadIdx.x;
  const int pd = gid & 63;
  const int row = gid >> 6;      // b*H*L + h*L + l
  const int l = row & 2047;
  ushort_t* base = (blockIdx.y ? Kb : Qb) + (size_t)row * 128;
  const float a = bf2f(base[pd]);
  const float bv = bf2f(base[pd + 64]);
  const float invf_rev = exp2f(-(float)pd * 0.20762050593045702f) * 0.15915494309189535f;
  float rev = (float)l * invf_rev;
  rev -= floorf(rev);
  const float ang = rev * 6.283185307179586f;
  float s, c;
  __sincosf(ang, &s, &c);
  float na = a * c - bv * s;
  float nb = bv * c + a * s;
  if (blockIdx.y == 0) { na *= 0.08838834764831845f; nb *= 0.08838834764831845f; }
  base[pd] = f2bf(na);
  base[pd + 64] = f2bf(nb);
}

// ---------------------------------------------------------------- V transpose per head
__global__ __launch_bounds__(256) void vtrans_kernel(const ushort_t* __restrict__ Vn,
                                                     ushort_t* __restrict__ Vt) {
  __shared__ ushort_t ls[128 * 132];
  const int bh = blockIdx.x >> 4;
  const int l0 = (blockIdx.x & 15) * 128;
  const int t = threadIdx.x;
  const ushort_t* src = Vn + ((size_t)bh * 2048 + l0) * 128;
#pragma unroll
  for (int it = 0; it < 16; ++it) {
    const int c = it * 256 + t;
    const int lr = c >> 5, dc = (c & 31) * 4;
    *(usvec4*)(ls + lr * 132 + dc) = *(const usvec4*)(src + lr * 128 + dc);
  }
  __syncthreads();
  ushort_t* dstb = Vt + (size_t)bh * 128 * 2048 + l0;
#pragma unroll
  for (int it = 0; it < 16; ++it) {
    const int c = it * 256 + t;
    const int d = c >> 5, lc = (c & 31) * 4;
    usvec4 o;
    o[0] = ls[(lc + 0) * 132 + d];
    o[1] = ls[(lc + 1) * 132 + d];
    o[2] = ls[(lc + 2) * 132 + d];
    o[3] = ls[(lc + 3) * 132 + d];
    *(usvec4*)(dstb + (size_t)d * 2048 + lc) = o;
  }
}

// ---------------------------------------------------------------- flash attention v2
// (round-4 version: mask precompute + split QK chains; unchanged this round)
__global__ __launch_bounds__(256, 2) void flash_kernel(
    const ushort_t* __restrict__ Qb, const ushort_t* __restrict__ Kb,
    const ushort_t* __restrict__ Vt, const int* __restrict__ am,
    ushort_t* __restrict__ Y) {
  __shared__ __align__(16) ushort_t lK[2][8192];
  __shared__ __align__(16) ushort_t lV[2][8192];
  __shared__ float lds_l[128];

  const int tid = threadIdx.x, wv = tid >> 6, lane = tid & 63;
  const int lh = lane >> 5, cq = lane & 31;
  const int bid = blockIdx.x;
  const int bh = bid & 31;
  const int qi = 15 - (bid >> 5);
  const int b = bh >> 4, head = bh & 15;
  const size_t qkBase = (size_t)bh * (2048 * 128);
  const int qb = qi * 128 + wv * 32;
  const int q = qb + cq;

  unsigned fullbits = 0;
  {
    const int* amr = am + b * 2048;
#pragma unroll
    for (int rgn = 0; rgn < 4; ++rgn) {
      const int4 a0 = *(const int4*)(amr + rgn * 512 + lane * 8);
      const int4 a1 = *(const int4*)(amr + rgn * 512 + lane * 8 + 4);
      const bool ok8 = a0.x && a0.y && a0.z && a0.w && a1.x && a1.y && a1.z && a1.w;
      const unsigned long long bal = __ballot(ok8);
#pragma unroll
      for (int tt = 0; tt < 8; ++tt)
        fullbits |= ((((bal >> (8 * tt)) & 0xFFull) == 0xFFull) ? 1u : 0u) << (rgn * 8 + tt);
    }
  }

  short8 qf[8];
  {
    const ushort_t* qrow = Qb + qkBase + (size_t)q * 128;
#pragma unroll
    for (int c = 0; c < 8; ++c) qf[c] = *(const short8*)(qrow + c * 16 + lh * 8);
  }

  fvec16 yacc[4];
#pragma unroll
  for (int i = 0; i < 4; ++i)
#pragma unroll
    for (int r = 0; r < 16; ++r) yacc[i][r] = 0.f;
  float psum = 0.f;

#define FLASH_STAGE(dK, dV, kk0)                                                          \
  _Pragma("unroll")                                                                       \
  for (int it = 0; it < 4; ++it) {                                                        \
    const int f_ = it * 4 + wv;                                                           \
    const int ct_ = f_ >> 3, c_ = f_ & 7;                                                 \
    glds16(Kb + qkBase + (size_t)((kk0) + ct_ * 32 + cq) * 128 + c_ * 16 + lh * 8,        \
           (dK) + f_ * 512);                                                              \
    const int dt_ = f_ >> 2, kc_ = f_ & 3;                                                \
    glds16(Vt + ((size_t)bh * 128 + dt_ * 32 + cq) * 2048 + (kk0) + kc_ * 16 + lh * 8,    \
           (dV) + f_ * 512);                                                              \
  }

  const int nt = qi * 2 + 2;
  FLASH_STAGE(&lK[0][0], &lV[0][0], 0)
  __syncthreads();

  int cur = 0;
  for (int t = 0; t < nt; ++t) {
    const int k0 = t * 64;
    if (t + 1 < nt) {
      FLASH_STAGE(&lK[cur ^ 1][0], &lV[cur ^ 1][0], k0 + 64)
    }

    if (k0 <= qb + 31) {
      const ushort_t* bK = &lK[cur][0];
      const ushort_t* bV = &lV[cur][0];
      const bool maskfull = (fullbits >> t) & 1u;
      unsigned long long keymask = ~0ull;
      if (!maskfull) keymask = __ballot(am[b * 2048 + k0 + lane] != 0);
      const bool fullvalid = (k0 + 63 <= qb) && maskfull;

#pragma unroll
      for (int ct = 0; ct < 2; ++ct) {
        fvec16 sA_, sB_;
#pragma unroll
        for (int r = 0; r < 16; ++r) { sA_[r] = 0.f; sB_[r] = 0.f; }
        __builtin_amdgcn_s_setprio(1);
#pragma unroll
        for (int c = 0; c < 4; ++c) {
          short8 kf = *(const short8*)(bK + (ct * 8 + c) * 512 + lane * 8);
          sA_ = __builtin_amdgcn_mfma_f32_32x32x16_bf16(kf, qf[c], sA_, 0, 0, 0);
        }
#pragma unroll
        for (int c = 4; c < 8; ++c) {
          short8 kf = *(const short8*)(bK + (ct * 8 + c) * 512 + lane * 8);
          sB_ = __builtin_amdgcn_mfma_f32_32x32x16_bf16(kf, qf[c], sB_, 0, 0, 0);
        }
        __builtin_amdgcn_s_setprio(0);
        float p[16];
        if (fullvalid) {
#pragma unroll
          for (int r = 0; r < 16; ++r) p[r] = __expf(sA_[r] + sB_[r]);
        } else {
#pragma unroll
          for (int r = 0; r < 16; ++r) {
            const int kl = (r & 3) + 8 * (r >> 2) + 4 * lh + ct * 32;
            const bool ok = (k0 + kl <= q) && (((keymask >> kl) & 1ull) != 0);
            p[r] = ok ? __expf(sA_[r] + sB_[r]) : 0.f;
          }
        }
#pragma unroll
        for (int r = 0; r < 16; ++r) psum += p[r];
        unsigned pk[8];
#pragma unroll
        for (int j = 0; j < 8; ++j) {
          __hip_bfloat162 t2 = __float22bfloat162_rn(make_float2(p[2 * j], p[2 * j + 1]));
          pk[j] = *(unsigned*)&t2;
        }
#pragma unroll
        for (int kc2 = 0; kc2 < 2; ++kc2) {
          unsigned a0 = pk[kc2 * 4 + 0], a2 = pk[kc2 * 4 + 2];
          unsigned a1 = pk[kc2 * 4 + 1], a3 = pk[kc2 * 4 + 3];
          swap32(a0, a2);
          swap32(a1, a3);
          union { unsigned u[4]; short8 s; } pf;
          pf.u[0] = a0; pf.u[1] = a1; pf.u[2] = a2; pf.u[3] = a3;
          const int kc = ct * 2 + kc2;
          __builtin_amdgcn_s_setprio(1);
#pragma unroll
          for (int dt = 0; dt < 4; ++dt) {
            short8 vf = *(const short8*)(bV + (dt * 4 + kc) * 512 + lane * 8);
            yacc[dt] = __builtin_amdgcn_mfma_f32_32x32x16_bf16(pf.s, vf, yacc[dt], 0, 0, 0);
          }
          __builtin_amdgcn_s_setprio(0);
        }
      }
    }
    __syncthreads();
    cur ^= 1;
  }
#undef FLASH_STAGE

  psum += __shfl_xor(psum, 32);
  if (lane < 32) lds_l[wv * 32 + lane] = psum;
  float inv16[16];
#pragma unroll
  for (int r = 0; r < 16; ++r)
    inv16[r] = 1.f / lds_l[wv * 32 + (r & 3) + 8 * (r >> 2) + 4 * lh];

#pragma unroll
  for (int dt = 0; dt < 4; ++dt)
#pragma unroll
    for (int r = 0; r < 16; ++r) {
      const int qloc = (r & 3) + 8 * (r >> 2) + 4 * lh;
      ushort_t* dst = Y + ((size_t)(b * 2048 + qb + qloc)) * 2048 + head * 128 + dt * 32 + cq;
      *dst = f2bf(yacc[dt][r] * inv16[r]);
    }
}

// ---------------------------------------------------------------- launch
extern "C" void kernel_launch(void* const* d_in, const int* in_sizes, int n_in,
                              void* d_out, int out_size, void* d_ws, size_t ws_size,
                              hipStream_t stream) {
  const float* x      = (const float*)d_in[0];
  const int*   amask  = (const int*)d_in[1];
  const float* w_qkv  = (const float*)d_in[2];
  const float* w_proj = (const float*)d_in[3];

  ushort_t* xb     = (ushort_t*)d_ws;          // 8,388,608   (dead after gemm1)
  ushort_t* wqkvT  = xb + 8388608;             // 12,582,912  (dead after gemm1)
  ushort_t* wprojT = wqkvT + 12582912;         // 4,194,304
  ushort_t* Qb     = wprojT + 4194304;         // 8,388,608
  ushort_t* Kb     = Qb + 8388608;             // 8,388,608
  ushort_t* Vn     = Kb + 8388608;             // 8,388,608  -> total 96 MiB
  ushort_t* Vt     = wqkvT;                    // reuse
  ushort_t* Yb     = xb;                       // reuse

  cast_f32_bf16<<<8192, 256, 0, stream>>>(x, xb);
  tcast<<<dim3(96, 32), 256, 0, stream>>>(w_qkv, wqkvT, 2048, 6144);
  tcast<<<dim3(32, 32), 256, 0, stream>>>(w_proj, wprojT, 2048, 2048);
  gemm192<<<512, 512, 0, stream>>>(xb, wqkvT, 4096, 6144, 2048, 1,
                                   nullptr, Qb, Kb, Vn);
  rope_kernel<<<dim3(16384, 2), 256, 0, stream>>>(Qb, Kb);
  vtrans_kernel<<<512, 256, 0, stream>>>(Vn, Vt);
  flash_kernel<<<512, 256, 0, stream>>>(Qb, Kb, Vt, amask, Yb);
  gemm128<<<256, 512, 0, stream>>>(Yb, wprojT, 4096, 2048, 2048, 0,
                                   (float*)d_out, nullptr, nullptr, nullptr);
}